// Round 2
// baseline (1629.871 us; speedup 1.0000x reference)
//
#include <hip/hip_runtime.h>
#include <hip/hip_bf16.h>

#define NN    50000   // nodes
#define E0C   400000  // raw edges
#define ETOT  450000  // + self loops
#define HH    8
#define FF    512     // H*C layers 1-2
#define F3    40      // H*C3 layer 3
#define C3    5

// ---------------- utility ----------------
__global__ void zero_int_kernel(int* p, int n) {
    int i = blockIdx.x * blockDim.x + threadIdx.x;
    if (i < n) p[i] = 0;
}

// ---------------- CSR build ----------------
__global__ void count_kernel(const int* __restrict__ ei, int* __restrict__ cnt) {
    int e = blockIdx.x * blockDim.x + threadIdx.x;
    if (e >= ETOT) return;
    int dst = (e < E0C) ? ei[E0C + e] : (e - E0C);
    atomicAdd(&cnt[dst], 1);
}

__global__ __launch_bounds__(1024) void scan_kernel(const int* __restrict__ cnt,
                                                    int* __restrict__ offs, int n) {
    __shared__ int s[1024];
    __shared__ int carry_sh;
    int tid = threadIdx.x;
    if (tid == 0) carry_sh = 0;
    __syncthreads();
    for (int base = 0; base < n; base += 1024) {
        int i = base + tid;
        s[tid] = (i < n) ? cnt[i] : 0;
        __syncthreads();
        for (int d = 1; d < 1024; d <<= 1) {
            int add = (tid >= d) ? s[tid - d] : 0;
            __syncthreads();
            s[tid] += add;
            __syncthreads();
        }
        int c = carry_sh;
        if (i < n) offs[i + 1] = c + s[tid];
        __syncthreads();
        if (tid == 1023) carry_sh = c + s[1023];
        __syncthreads();
    }
    if (tid == 0) offs[0] = 0;
}

__global__ void scatter_kernel(const int* __restrict__ ei, const int* __restrict__ offs,
                               int* __restrict__ cur, int* __restrict__ srcs) {
    int e = blockIdx.x * blockDim.x + threadIdx.x;
    if (e >= ETOT) return;
    int src, dst;
    if (e < E0C) { src = ei[e]; dst = ei[E0C + e]; }
    else         { src = dst = e - E0C; }
    int pos = offs[dst] + atomicAdd(&cur[dst], 1);
    srcs[pos] = src;
}

// ---------------- layer 1 GEMM (K=12) fused with attention logits ----------------
__global__ __launch_bounds__(512) void gemm1_fused(
    const float* __restrict__ x, const float* __restrict__ W1,
    const float* __restrict__ as1, const float* __restrict__ ad1,
    float* __restrict__ h, float* __restrict__ al_s, float* __restrict__ al_d) {
    int n = blockIdx.x;
    int t = threadIdx.x;
    __shared__ float xs[12];
    if (t < 12) xs[t] = x[n * 12 + t];
    __syncthreads();
    float acc = 0.f;
#pragma unroll
    for (int k = 0; k < 12; ++k) acc += xs[k] * W1[k * FF + t];
    h[(size_t)n * FF + t] = acc;
    int head = t >> 6;
    float ps = acc * as1[t];
    float pd = acc * ad1[t];
#pragma unroll
    for (int d = 32; d; d >>= 1) {
        ps += __shfl_down(ps, d);
        pd += __shfl_down(pd, d);
    }
    if ((t & 63) == 0) {
        al_s[n * HH + head] = ps;
        al_d[n * HH + head] = pd;
    }
}

// ---------------- attention logits for 512-wide h ----------------
__global__ __launch_bounds__(512) void al512_kernel(
    const float* __restrict__ h, const float* __restrict__ a_src,
    const float* __restrict__ a_dst, float* __restrict__ al_s, float* __restrict__ al_d) {
    int n = blockIdx.x;
    int t = threadIdx.x;
    int head = t >> 6;
    float v = h[(size_t)n * FF + t];
    float ps = v * a_src[t];
    float pd = v * a_dst[t];
#pragma unroll
    for (int d = 32; d; d >>= 1) {
        ps += __shfl_down(ps, d);
        pd += __shfl_down(pd, d);
    }
    if ((t & 63) == 0) {
        al_s[n * HH + head] = ps;
        al_d[n * HH + head] = pd;
    }
}

// ---------------- attention aggregate, 512-wide (layers 1,2) ----------------
__global__ __launch_bounds__(512) void attn512_kernel(
    const float* __restrict__ h, const float* __restrict__ al_s,
    const float* __restrict__ al_d, const int* __restrict__ offs,
    const int* __restrict__ srcs, const float* __restrict__ bias,
    float* __restrict__ out, int relu) {
    int n = blockIdx.x;
    int t = threadIdx.x;
    int head = t >> 6;
    int beg = offs[n], end = offs[n + 1];
    __shared__ float m_s[HH], idn_s[HH], ald_sh[HH];
    if (t < HH) ald_sh[t] = al_d[n * HH + t];
    __syncthreads();
    if (t < HH) {
        float ald = ald_sh[t];
        float m = -1e30f;
        for (int e = beg; e < end; ++e) {
            int s = srcs[e];
            float sc = al_s[s * HH + t] + ald;
            sc = sc > 0.f ? sc : 0.2f * sc;
            m = fmaxf(m, sc);
        }
        float den = 0.f;
        for (int e = beg; e < end; ++e) {
            int s = srcs[e];
            float sc = al_s[s * HH + t] + ald;
            sc = sc > 0.f ? sc : 0.2f * sc;
            den += __expf(sc - m);
        }
        m_s[t] = m;
        idn_s[t] = 1.f / (den + 1e-16f);
    }
    __syncthreads();
    float m = m_s[head], idn = idn_s[head], ald = ald_sh[head];
    float acc = 0.f;
    for (int e = beg; e < end; ++e) {
        int s = srcs[e];
        float sc = al_s[s * HH + head] + ald;
        sc = sc > 0.f ? sc : 0.2f * sc;
        float a = __expf(sc - m) * idn;
        acc += a * h[(size_t)s * FF + t];
    }
    float v = acc + bias[t];
    if (relu) v = fmaxf(v, 0.f);
    out[(size_t)n * FF + t] = v;
}

// ---------------- generic fp32 tiled GEMM: C[M,N] = A[M,K] @ B[K,N] ----------------
__global__ __launch_bounds__(256) void gemm_tiled(
    const float* __restrict__ A, const float* __restrict__ B, float* __restrict__ C,
    int M, int N, int K) {
    __shared__ float As[16][68];
    __shared__ float Bs[16][64];
    int tid = threadIdx.x;
    int tx = tid & 15, ty = tid >> 4;
    int m0 = blockIdx.x * 64, n0 = blockIdx.y * 64;
    float acc[4][4] = {};
    int arow = tid >> 2;          // 0..63
    int akq = (tid & 3) * 4;      // 0,4,8,12
    int bk  = tid >> 4;           // 0..15
    int bnq = (tid & 15) * 4;     // 0..60
    for (int k0 = 0; k0 < K; k0 += 16) {
        {
            int grow = m0 + arow;
            if (grow < M) {
                const float* p = &A[(size_t)grow * K + k0 + akq];
                float4 v = *(const float4*)p;
                As[akq + 0][arow] = v.x; As[akq + 1][arow] = v.y;
                As[akq + 2][arow] = v.z; As[akq + 3][arow] = v.w;
            } else {
                As[akq + 0][arow] = 0.f; As[akq + 1][arow] = 0.f;
                As[akq + 2][arow] = 0.f; As[akq + 3][arow] = 0.f;
            }
        }
        {
            int gn = n0 + bnq;
            const float* p = &B[(size_t)(k0 + bk) * N + gn];
            if (gn + 3 < N) {
                *(float4*)&Bs[bk][bnq] = *(const float4*)p;
            } else {
#pragma unroll
                for (int j = 0; j < 4; ++j)
                    Bs[bk][bnq + j] = (gn + j < N) ? p[j] : 0.f;
            }
        }
        __syncthreads();
#pragma unroll
        for (int k = 0; k < 16; ++k) {
            float4 a4 = *(const float4*)&As[k][ty * 4];
            float4 b4 = *(const float4*)&Bs[k][tx * 4];
            float av[4] = {a4.x, a4.y, a4.z, a4.w};
            float bv[4] = {b4.x, b4.y, b4.z, b4.w};
#pragma unroll
            for (int i = 0; i < 4; ++i)
#pragma unroll
                for (int j = 0; j < 4; ++j)
                    acc[i][j] += av[i] * bv[j];
        }
        __syncthreads();
    }
#pragma unroll
    for (int i = 0; i < 4; ++i) {
        int r = m0 + ty * 4 + i;
        if (r >= M) continue;
#pragma unroll
        for (int j = 0; j < 4; ++j) {
            int cidx = n0 + tx * 4 + j;
            if (cidx < N) C[(size_t)r * N + cidx] = acc[i][j];
        }
    }
}

// ---------------- layer-3 attention logits (F=40, C=5) ----------------
__global__ void al40_kernel(const float* __restrict__ h3, const float* __restrict__ as3,
                            const float* __restrict__ ad3, float* __restrict__ al_s,
                            float* __restrict__ al_d) {
    int n = blockIdx.x * blockDim.x + threadIdx.x;
    if (n >= NN) return;
#pragma unroll
    for (int hh = 0; hh < HH; ++hh) {
        float s = 0.f, d = 0.f;
#pragma unroll
        for (int c = 0; c < C3; ++c) {
            float v = h3[(size_t)n * F3 + hh * C3 + c];
            s += v * as3[hh * C3 + c];
            d += v * ad3[hh * C3 + c];
        }
        al_s[n * HH + hh] = s;
        al_d[n * HH + hh] = d;
    }
}

// ---------------- layer-3 attention + head-mean + bias + log_softmax ----------------
__global__ __launch_bounds__(64) void attn3_kernel(
    const float* __restrict__ h3, const float* __restrict__ al_s,
    const float* __restrict__ al_d, const int* __restrict__ offs,
    const int* __restrict__ srcs, const float* __restrict__ b3,
    float* __restrict__ out) {
    int n = blockIdx.x;
    int t = threadIdx.x;
    int beg = offs[n], end = offs[n + 1];
    __shared__ float m_s[HH], idn_s[HH], ald_sh[HH];
    __shared__ float accs[HH][C3];
    __shared__ float vv[C3];
    if (t < HH) ald_sh[t] = al_d[n * HH + t];
    __syncthreads();
    if (t < HH) {
        float ald = ald_sh[t];
        float m = -1e30f;
        for (int e = beg; e < end; ++e) {
            int s = srcs[e];
            float sc = al_s[s * HH + t] + ald;
            sc = sc > 0.f ? sc : 0.2f * sc;
            m = fmaxf(m, sc);
        }
        float den = 0.f;
        for (int e = beg; e < end; ++e) {
            int s = srcs[e];
            float sc = al_s[s * HH + t] + ald;
            sc = sc > 0.f ? sc : 0.2f * sc;
            den += __expf(sc - m);
        }
        m_s[t] = m;
        idn_s[t] = 1.f / (den + 1e-16f);
    }
    __syncthreads();
    if (t < F3) {
        int hh = t / C3;
        int c = t - hh * C3;
        float m = m_s[hh], idn = idn_s[hh], ald = ald_sh[hh];
        float acc = 0.f;
        for (int e = beg; e < end; ++e) {
            int s = srcs[e];
            float sc = al_s[s * HH + hh] + ald;
            sc = sc > 0.f ? sc : 0.2f * sc;
            float a = __expf(sc - m) * idn;
            acc += a * h3[(size_t)s * F3 + t];
        }
        accs[hh][c] = acc;
    }
    __syncthreads();
    if (t < C3) {
        float s = 0.f;
#pragma unroll
        for (int hh = 0; hh < HH; ++hh) s += accs[hh][t];
        vv[t] = s * 0.125f + b3[t];
    }
    __syncthreads();
    if (t < C3) {
        float mx = vv[0];
#pragma unroll
        for (int c = 1; c < C3; ++c) mx = fmaxf(mx, vv[c]);
        float se = 0.f;
#pragma unroll
        for (int c = 0; c < C3; ++c) se += __expf(vv[c] - mx);
        out[(size_t)n * C3 + t] = vv[t] - mx - logf(se);
    }
}

// ---------------- host launcher ----------------
extern "C" void kernel_launch(void* const* d_in, const int* in_sizes, int n_in,
                              void* d_out, int out_size, void* d_ws, size_t ws_size,
                              hipStream_t stream) {
    const float* x   = (const float*)d_in[0];
    const int*   ei  = (const int*)d_in[1];
    const float* W1  = (const float*)d_in[2];
    const float* as1 = (const float*)d_in[3];
    const float* ad1 = (const float*)d_in[4];
    const float* b1  = (const float*)d_in[5];
    const float* W2  = (const float*)d_in[6];
    const float* as2 = (const float*)d_in[7];
    const float* ad2 = (const float*)d_in[8];
    const float* b2  = (const float*)d_in[9];
    const float* W3  = (const float*)d_in[10];
    const float* as3 = (const float*)d_in[11];
    const float* ad3 = (const float*)d_in[12];
    const float* b3  = (const float*)d_in[13];
    float* out = (float*)d_out;

    char* p = (char*)d_ws;
    auto alloc = [&](size_t bytes) {
        void* r = (void*)p;
        p += (bytes + 255) & ~(size_t)255;
        return r;
    };
    float* Abuf = (float*)alloc((size_t)NN * FF * 4);
    float* Bbuf = (float*)alloc((size_t)NN * FF * 4);
    float* h3   = (float*)alloc((size_t)NN * F3 * 4);
    float* alS  = (float*)alloc((size_t)NN * HH * 4);
    float* alD  = (float*)alloc((size_t)NN * HH * 4);
    int* offs   = (int*)alloc((size_t)(NN + 1) * 4);
    int* cnt    = (int*)alloc((size_t)NN * 4);
    int* srcs   = (int*)alloc((size_t)ETOT * 4);

    // ---- CSR build (dst-sorted) ----
    zero_int_kernel<<<(NN + 255) / 256, 256, 0, stream>>>(cnt, NN);
    count_kernel<<<(ETOT + 255) / 256, 256, 0, stream>>>(ei, cnt);
    scan_kernel<<<1, 1024, 0, stream>>>(cnt, offs, NN);
    zero_int_kernel<<<(NN + 255) / 256, 256, 0, stream>>>(cnt, NN);
    scatter_kernel<<<(ETOT + 255) / 256, 256, 0, stream>>>(ei, offs, cnt, srcs);

    // ---- layer 1 ----
    gemm1_fused<<<NN, 512, 0, stream>>>(x, W1, as1, ad1, Abuf, alS, alD);
    attn512_kernel<<<NN, 512, 0, stream>>>(Abuf, alS, alD, offs, srcs, b1, Bbuf, 1);

    // ---- layer 2 ----
    gemm_tiled<<<dim3((NN + 63) / 64, FF / 64), 256, 0, stream>>>(Bbuf, W2, Abuf, NN, FF, FF);
    al512_kernel<<<NN, 512, 0, stream>>>(Abuf, as2, ad2, alS, alD);
    attn512_kernel<<<NN, 512, 0, stream>>>(Abuf, alS, alD, offs, srcs, b2, Bbuf, 1);

    // ---- layer 3 ----
    gemm_tiled<<<dim3((NN + 63) / 64, 1), 256, 0, stream>>>(Bbuf, W3, h3, NN, F3, FF);
    al40_kernel<<<(NN + 255) / 256, 256, 0, stream>>>(h3, as3, ad3, alS, alD);
    attn3_kernel<<<NN, 64, 0, stream>>>(h3, alS, alD, offs, srcs, b3, out);
}

// Round 3
// 1157.299 us; speedup vs baseline: 1.4083x; 1.4083x over previous
//
#include <hip/hip_runtime.h>
#include <hip/hip_bf16.h>

#define NN    50000   // nodes
#define E0C   400000  // raw edges
#define ETOT  450000  // + self loops
#define HH    8
#define FF    512     // H*C layers 1-2
#define F3    40      // H*C3 layer 3
#define C3    5
#define MAXE  128     // LDS alpha-cache capacity (deg ~ Poisson(8)+1, tail @128 ~ 0)

// ---------------- utility ----------------
__global__ void zero_int_kernel(int* p, int n) {
    int i = blockIdx.x * blockDim.x + threadIdx.x;
    if (i < n) p[i] = 0;
}

// ---------------- CSR build ----------------
__global__ void count_kernel(const int* __restrict__ ei, int* __restrict__ cnt) {
    int e = blockIdx.x * blockDim.x + threadIdx.x;
    if (e >= ETOT) return;
    int dst = (e < E0C) ? ei[E0C + e] : (e - E0C);
    atomicAdd(&cnt[dst], 1);
}

__global__ __launch_bounds__(1024) void scan_kernel(const int* __restrict__ cnt,
                                                    int* __restrict__ offs, int n) {
    __shared__ int s[1024];
    __shared__ int carry_sh;
    int tid = threadIdx.x;
    if (tid == 0) carry_sh = 0;
    __syncthreads();
    for (int base = 0; base < n; base += 1024) {
        int i = base + tid;
        s[tid] = (i < n) ? cnt[i] : 0;
        __syncthreads();
        for (int d = 1; d < 1024; d <<= 1) {
            int add = (tid >= d) ? s[tid - d] : 0;
            __syncthreads();
            s[tid] += add;
            __syncthreads();
        }
        int c = carry_sh;
        if (i < n) offs[i + 1] = c + s[tid];
        __syncthreads();
        if (tid == 1023) carry_sh = c + s[1023];
        __syncthreads();
    }
    if (tid == 0) offs[0] = 0;
}

__global__ void scatter_kernel(const int* __restrict__ ei, const int* __restrict__ offs,
                               int* __restrict__ cur, int* __restrict__ srcs) {
    int e = blockIdx.x * blockDim.x + threadIdx.x;
    if (e >= ETOT) return;
    int src, dst;
    if (e < E0C) { src = ei[e]; dst = ei[E0C + e]; }
    else         { src = dst = e - E0C; }
    int pos = offs[dst] + atomicAdd(&cur[dst], 1);
    srcs[pos] = src;
}

// ---------------- layer 1 GEMM (K=12) fused with attention logits ----------------
__global__ __launch_bounds__(512) void gemm1_fused(
    const float* __restrict__ x, const float* __restrict__ W1,
    const float* __restrict__ as1, const float* __restrict__ ad1,
    float* __restrict__ h, float* __restrict__ al_s, float* __restrict__ al_d) {
    int n = blockIdx.x;
    int t = threadIdx.x;
    __shared__ float xs[12];
    if (t < 12) xs[t] = x[n * 12 + t];
    __syncthreads();
    float acc = 0.f;
#pragma unroll
    for (int k = 0; k < 12; ++k) acc += xs[k] * W1[k * FF + t];
    h[(size_t)n * FF + t] = acc;
    int head = t >> 6;
    float ps = acc * as1[t];
    float pd = acc * ad1[t];
#pragma unroll
    for (int d = 32; d; d >>= 1) {
        ps += __shfl_down(ps, d);
        pd += __shfl_down(pd, d);
    }
    if ((t & 63) == 0) {
        al_s[n * HH + head] = ps;
        al_d[n * HH + head] = pd;
    }
}

// ---------------- attention logits for 512-wide h ----------------
__global__ __launch_bounds__(512) void al512_kernel(
    const float* __restrict__ h, const float* __restrict__ a_src,
    const float* __restrict__ a_dst, float* __restrict__ al_s, float* __restrict__ al_d) {
    int n = blockIdx.x;
    int t = threadIdx.x;
    int head = t >> 6;
    float v = h[(size_t)n * FF + t];
    float ps = v * a_src[t];
    float pd = v * a_dst[t];
#pragma unroll
    for (int d = 32; d; d >>= 1) {
        ps += __shfl_down(ps, d);
        pd += __shfl_down(pd, d);
    }
    if ((t & 63) == 0) {
        al_s[n * HH + head] = ps;
        al_d[n * HH + head] = pd;
    }
}

// ---------------- attention aggregate, 512-wide (layers 1,2) ----------------
// 8 waves/block; wave w owns head w for the softmax (lanes parallel over edges,
// shuffle-reduce). alpha + srcs cached in LDS -> gather loop has no dependent
// global chains except the h-row load itself.
__global__ __launch_bounds__(512) void attn512_kernel(
    const float* __restrict__ h, const float* __restrict__ al_s,
    const float* __restrict__ al_d, const int* __restrict__ offs,
    const int* __restrict__ srcs, const float* __restrict__ bias,
    float* __restrict__ out, int relu) {
    int n = blockIdx.x;
    int t = threadIdx.x;
    int wave = t >> 6, lane = t & 63;
    int beg = offs[n], end = offs[n + 1];
    int deg = end - beg;

    __shared__ float alpha_sh[HH][MAXE];
    __shared__ int   srcs_sh[MAXE];
    __shared__ float m_s[HH], idn_s[HH], ald_sh[HH];

    // ---- phase 1: wave-parallel softmax, head = wave ----
    float ald = al_d[n * HH + wave];
    float m = -1e30f;
    for (int e = beg + lane; e < end; e += 64) {
        int s = srcs[e];
        if (wave == 0 && (e - beg) < MAXE) srcs_sh[e - beg] = s;
        float sc = al_s[s * HH + wave] + ald;
        sc = sc > 0.f ? sc : 0.2f * sc;
        m = fmaxf(m, sc);
    }
#pragma unroll
    for (int d = 32; d; d >>= 1) m = fmaxf(m, __shfl_xor(m, d));
    float den = 0.f;
    if (deg <= MAXE) {
        for (int e = beg + lane; e < end; e += 64) {
            int s = srcs[e];
            float sc = al_s[s * HH + wave] + ald;
            sc = sc > 0.f ? sc : 0.2f * sc;
            float ex = __expf(sc - m);
            den += ex;
            alpha_sh[wave][e - beg] = ex;
        }
    } else {
        for (int e = beg + lane; e < end; e += 64) {
            int s = srcs[e];
            float sc = al_s[s * HH + wave] + ald;
            sc = sc > 0.f ? sc : 0.2f * sc;
            den += __expf(sc - m);
        }
    }
#pragma unroll
    for (int d = 32; d; d >>= 1) den += __shfl_xor(den, d);
    float idn = 1.f / (den + 1e-16f);
    if (deg <= MAXE) {
        for (int e = beg + lane; e < end; e += 64)
            alpha_sh[wave][e - beg] *= idn;
    }
    if (lane == 0) { m_s[wave] = m; idn_s[wave] = idn; ald_sh[wave] = ald; }
    __syncthreads();

    // ---- phase 2: gather-aggregate ----
    int head = wave;
    float acc = 0.f;
    if (deg <= MAXE) {
#pragma unroll 4
        for (int j = 0; j < deg; ++j) {
            int s = srcs_sh[j];
            float a = alpha_sh[head][j];
            acc += a * h[(size_t)s * FF + t];
        }
    } else {
        float mm = m_s[head], iidn = idn_s[head], aald = ald_sh[head];
        for (int e = beg; e < end; ++e) {
            int s = srcs[e];
            float sc = al_s[s * HH + head] + aald;
            sc = sc > 0.f ? sc : 0.2f * sc;
            float a = __expf(sc - mm) * iidn;
            acc += a * h[(size_t)s * FF + t];
        }
    }
    float v = acc + bias[t];
    if (relu) v = fmaxf(v, 0.f);
    out[(size_t)n * FF + t] = v;
}

// ---------------- generic fp32 tiled GEMM: C[M,N] = A[M,K] @ B[K,N] ----------------
__global__ __launch_bounds__(256) void gemm_tiled(
    const float* __restrict__ A, const float* __restrict__ B, float* __restrict__ C,
    int M, int N, int K) {
    __shared__ float As[16][68];
    __shared__ float Bs[16][64];
    int tid = threadIdx.x;
    int tx = tid & 15, ty = tid >> 4;
    int m0 = blockIdx.x * 64, n0 = blockIdx.y * 64;
    float acc[4][4] = {};
    int arow = tid >> 2;          // 0..63
    int akq = (tid & 3) * 4;      // 0,4,8,12
    int bk  = tid >> 4;           // 0..15
    int bnq = (tid & 15) * 4;     // 0..60
    for (int k0 = 0; k0 < K; k0 += 16) {
        {
            int grow = m0 + arow;
            if (grow < M) {
                const float* p = &A[(size_t)grow * K + k0 + akq];
                float4 v = *(const float4*)p;
                As[akq + 0][arow] = v.x; As[akq + 1][arow] = v.y;
                As[akq + 2][arow] = v.z; As[akq + 3][arow] = v.w;
            } else {
                As[akq + 0][arow] = 0.f; As[akq + 1][arow] = 0.f;
                As[akq + 2][arow] = 0.f; As[akq + 3][arow] = 0.f;
            }
        }
        {
            int gn = n0 + bnq;
            const float* p = &B[(size_t)(k0 + bk) * N + gn];
            if (gn + 3 < N) {
                *(float4*)&Bs[bk][bnq] = *(const float4*)p;
            } else {
#pragma unroll
                for (int j = 0; j < 4; ++j)
                    Bs[bk][bnq + j] = (gn + j < N) ? p[j] : 0.f;
            }
        }
        __syncthreads();
#pragma unroll
        for (int k = 0; k < 16; ++k) {
            float4 a4 = *(const float4*)&As[k][ty * 4];
            float4 b4 = *(const float4*)&Bs[k][tx * 4];
            float av[4] = {a4.x, a4.y, a4.z, a4.w};
            float bv[4] = {b4.x, b4.y, b4.z, b4.w};
#pragma unroll
            for (int i = 0; i < 4; ++i)
#pragma unroll
                for (int j = 0; j < 4; ++j)
                    acc[i][j] += av[i] * bv[j];
        }
        __syncthreads();
    }
#pragma unroll
    for (int i = 0; i < 4; ++i) {
        int r = m0 + ty * 4 + i;
        if (r >= M) continue;
#pragma unroll
        for (int j = 0; j < 4; ++j) {
            int cidx = n0 + tx * 4 + j;
            if (cidx < N) C[(size_t)r * N + cidx] = acc[i][j];
        }
    }
}

// ---------------- layer-3 attention logits (F=40, C=5) ----------------
__global__ void al40_kernel(const float* __restrict__ h3, const float* __restrict__ as3,
                            const float* __restrict__ ad3, float* __restrict__ al_s,
                            float* __restrict__ al_d) {
    int n = blockIdx.x * blockDim.x + threadIdx.x;
    if (n >= NN) return;
#pragma unroll
    for (int hh = 0; hh < HH; ++hh) {
        float s = 0.f, d = 0.f;
#pragma unroll
        for (int c = 0; c < C3; ++c) {
            float v = h3[(size_t)n * F3 + hh * C3 + c];
            s += v * as3[hh * C3 + c];
            d += v * ad3[hh * C3 + c];
        }
        al_s[n * HH + hh] = s;
        al_d[n * HH + hh] = d;
    }
}

// ---------------- layer-3 attention + head-mean + bias + log_softmax ----------------
__global__ __launch_bounds__(64) void attn3_kernel(
    const float* __restrict__ h3, const float* __restrict__ al_s,
    const float* __restrict__ al_d, const int* __restrict__ offs,
    const int* __restrict__ srcs, const float* __restrict__ b3,
    float* __restrict__ out) {
    int n = blockIdx.x;
    int t = threadIdx.x;
    int beg = offs[n], end = offs[n + 1];
    __shared__ float m_s[HH], idn_s[HH], ald_sh[HH];
    __shared__ float accs[HH][C3];
    __shared__ float vv[C3];
    if (t < HH) ald_sh[t] = al_d[n * HH + t];
    __syncthreads();
    if (t < HH) {
        float ald = ald_sh[t];
        float m = -1e30f;
        for (int e = beg; e < end; ++e) {
            int s = srcs[e];
            float sc = al_s[s * HH + t] + ald;
            sc = sc > 0.f ? sc : 0.2f * sc;
            m = fmaxf(m, sc);
        }
        float den = 0.f;
        for (int e = beg; e < end; ++e) {
            int s = srcs[e];
            float sc = al_s[s * HH + t] + ald;
            sc = sc > 0.f ? sc : 0.2f * sc;
            den += __expf(sc - m);
        }
        m_s[t] = m;
        idn_s[t] = 1.f / (den + 1e-16f);
    }
    __syncthreads();
    if (t < F3) {
        int hh = t / C3;
        int c = t - hh * C3;
        float m = m_s[hh], idn = idn_s[hh], ald = ald_sh[hh];
        float acc = 0.f;
        for (int e = beg; e < end; ++e) {
            int s = srcs[e];
            float sc = al_s[s * HH + hh] + ald;
            sc = sc > 0.f ? sc : 0.2f * sc;
            float a = __expf(sc - m) * idn;
            acc += a * h3[(size_t)s * F3 + t];
        }
        accs[hh][c] = acc;
    }
    __syncthreads();
    if (t < C3) {
        float s = 0.f;
#pragma unroll
        for (int hh = 0; hh < HH; ++hh) s += accs[hh][t];
        vv[t] = s * 0.125f + b3[t];
    }
    __syncthreads();
    if (t < C3) {
        float mx = vv[0];
#pragma unroll
        for (int c = 1; c < C3; ++c) mx = fmaxf(mx, vv[c]);
        float se = 0.f;
#pragma unroll
        for (int c = 0; c < C3; ++c) se += __expf(vv[c] - mx);
        out[(size_t)n * C3 + t] = vv[t] - mx - logf(se);
    }
}

// ---------------- host launcher ----------------
extern "C" void kernel_launch(void* const* d_in, const int* in_sizes, int n_in,
                              void* d_out, int out_size, void* d_ws, size_t ws_size,
                              hipStream_t stream) {
    const float* x   = (const float*)d_in[0];
    const int*   ei  = (const int*)d_in[1];
    const float* W1  = (const float*)d_in[2];
    const float* as1 = (const float*)d_in[3];
    const float* ad1 = (const float*)d_in[4];
    const float* b1  = (const float*)d_in[5];
    const float* W2  = (const float*)d_in[6];
    const float* as2 = (const float*)d_in[7];
    const float* ad2 = (const float*)d_in[8];
    const float* b2  = (const float*)d_in[9];
    const float* W3  = (const float*)d_in[10];
    const float* as3 = (const float*)d_in[11];
    const float* ad3 = (const float*)d_in[12];
    const float* b3  = (const float*)d_in[13];
    float* out = (float*)d_out;

    char* p = (char*)d_ws;
    auto alloc = [&](size_t bytes) {
        void* r = (void*)p;
        p += (bytes + 255) & ~(size_t)255;
        return r;
    };
    float* Abuf = (float*)alloc((size_t)NN * FF * 4);
    float* Bbuf = (float*)alloc((size_t)NN * FF * 4);
    float* h3   = (float*)alloc((size_t)NN * F3 * 4);
    float* alS  = (float*)alloc((size_t)NN * HH * 4);
    float* alD  = (float*)alloc((size_t)NN * HH * 4);
    int* offs   = (int*)alloc((size_t)(NN + 1) * 4);
    int* cnt    = (int*)alloc((size_t)NN * 4);
    int* srcs   = (int*)alloc((size_t)ETOT * 4);

    // ---- CSR build (dst-sorted) ----
    zero_int_kernel<<<(NN + 255) / 256, 256, 0, stream>>>(cnt, NN);
    count_kernel<<<(ETOT + 255) / 256, 256, 0, stream>>>(ei, cnt);
    scan_kernel<<<1, 1024, 0, stream>>>(cnt, offs, NN);
    zero_int_kernel<<<(NN + 255) / 256, 256, 0, stream>>>(cnt, NN);
    scatter_kernel<<<(ETOT + 255) / 256, 256, 0, stream>>>(ei, offs, cnt, srcs);

    // ---- layer 1 ----
    gemm1_fused<<<NN, 512, 0, stream>>>(x, W1, as1, ad1, Abuf, alS, alD);
    attn512_kernel<<<NN, 512, 0, stream>>>(Abuf, alS, alD, offs, srcs, b1, Bbuf, 1);

    // ---- layer 2 ----
    gemm_tiled<<<dim3((NN + 63) / 64, FF / 64), 256, 0, stream>>>(Bbuf, W2, Abuf, NN, FF, FF);
    al512_kernel<<<NN, 512, 0, stream>>>(Abuf, as2, ad2, alS, alD);
    attn512_kernel<<<NN, 512, 0, stream>>>(Abuf, alS, alD, offs, srcs, b2, Bbuf, 1);

    // ---- layer 3 ----
    gemm_tiled<<<dim3((NN + 63) / 64, 1), 256, 0, stream>>>(Bbuf, W3, h3, NN, F3, FF);
    al40_kernel<<<(NN + 255) / 256, 256, 0, stream>>>(h3, as3, ad3, alS, alD);
    attn3_kernel<<<NN, 64, 0, stream>>>(h3, alS, alD, offs, srcs, b3, out);
}

// Round 5
// 882.577 us; speedup vs baseline: 1.8467x; 1.3113x over previous
//
#include <hip/hip_runtime.h>
#include <hip/hip_bf16.h>

#define NN    50000   // nodes
#define MP    50048   // padded to 128*391 for MFMA GEMM
#define E0C   400000  // raw edges
#define ETOT  450000  // + self loops
#define HH    8
#define FF    512     // H*C layers 1-2
#define F3    40      // H*C3 layer 3
#define C3    5
#define MAXE  128     // LDS alpha-cache capacity

typedef __attribute__((ext_vector_type(8))) short bf16x8;
typedef __attribute__((ext_vector_type(4))) float f32x4;

__device__ inline unsigned short f2bf(float f) {
    union { float f; unsigned int u; } v; v.f = f;
    unsigned int r = v.u + 0x7FFF + ((v.u >> 16) & 1);
    return (unsigned short)(r >> 16);
}

// ---------------- utility ----------------
__global__ void zero_int_kernel(int* p, int n) {
    int i = blockIdx.x * blockDim.x + threadIdx.x;
    if (i < n) p[i] = 0;
}

__global__ void zero_tail_kernel(unsigned short* Ab16) {
    int i = blockIdx.x * blockDim.x + threadIdx.x;
    int total = (MP - NN) * FF;
    if (i < total) Ab16[(size_t)NN * FF + i] = 0;
}

// ---------------- CSR build ----------------
__global__ void count_kernel(const int* __restrict__ ei, int* __restrict__ cnt) {
    int e = blockIdx.x * blockDim.x + threadIdx.x;
    if (e >= ETOT) return;
    int dst = (e < E0C) ? ei[E0C + e] : (e - E0C);
    atomicAdd(&cnt[dst], 1);
}

__global__ __launch_bounds__(1024) void scan_kernel(const int* __restrict__ cnt,
                                                    int* __restrict__ offs, int n) {
    __shared__ int s[1024];
    __shared__ int carry_sh;
    int tid = threadIdx.x;
    if (tid == 0) carry_sh = 0;
    __syncthreads();
    for (int base = 0; base < n; base += 1024) {
        int i = base + tid;
        s[tid] = (i < n) ? cnt[i] : 0;
        __syncthreads();
        for (int d = 1; d < 1024; d <<= 1) {
            int add = (tid >= d) ? s[tid - d] : 0;
            __syncthreads();
            s[tid] += add;
            __syncthreads();
        }
        int c = carry_sh;
        if (i < n) offs[i + 1] = c + s[tid];
        __syncthreads();
        if (tid == 1023) carry_sh = c + s[1023];
        __syncthreads();
    }
    if (tid == 0) offs[0] = 0;
}

__global__ void scatter_kernel(const int* __restrict__ ei, const int* __restrict__ offs,
                               int* __restrict__ cur, int* __restrict__ srcs) {
    int e = blockIdx.x * blockDim.x + threadIdx.x;
    if (e >= ETOT) return;
    int src, dst;
    if (e < E0C) { src = ei[e]; dst = ei[E0C + e]; }
    else         { src = dst = e - E0C; }
    int pos = offs[dst] + atomicAdd(&cur[dst], 1);
    srcs[pos] = src;
}

// ---------------- layer 1 GEMM (K=12) fused with attention logits ----------------
__global__ __launch_bounds__(512) void gemm1_fused(
    const float* __restrict__ x, const float* __restrict__ W1,
    const float* __restrict__ as1, const float* __restrict__ ad1,
    float* __restrict__ h, float* __restrict__ al_s, float* __restrict__ al_d) {
    int n = blockIdx.x;
    int t = threadIdx.x;
    __shared__ float xs[12];
    if (t < 12) xs[t] = x[n * 12 + t];
    __syncthreads();
    float acc = 0.f;
#pragma unroll
    for (int k = 0; k < 12; ++k) acc += xs[k] * W1[k * FF + t];
    h[(size_t)n * FF + t] = acc;
    int head = t >> 6;
    float ps = acc * as1[t];
    float pd = acc * ad1[t];
#pragma unroll
    for (int d = 32; d; d >>= 1) {
        ps += __shfl_down(ps, d);
        pd += __shfl_down(pd, d);
    }
    if ((t & 63) == 0) {
        al_s[n * HH + head] = ps;
        al_d[n * HH + head] = pd;
    }
}

// ---------------- attention logits for 512-wide h ----------------
__global__ __launch_bounds__(512) void al512_kernel(
    const float* __restrict__ h, const float* __restrict__ a_src,
    const float* __restrict__ a_dst, float* __restrict__ al_s, float* __restrict__ al_d) {
    int n = blockIdx.x;
    int t = threadIdx.x;
    int head = t >> 6;
    float v = h[(size_t)n * FF + t];
    float ps = v * a_src[t];
    float pd = v * a_dst[t];
#pragma unroll
    for (int d = 32; d; d >>= 1) {
        ps += __shfl_down(ps, d);
        pd += __shfl_down(pd, d);
    }
    if ((t & 63) == 0) {
        al_s[n * HH + head] = ps;
        al_d[n * HH + head] = pd;
    }
}

// ---------------- attention aggregate, 512-wide (layers 1,2) ----------------
__global__ __launch_bounds__(512) void attn512_kernel(
    const float* __restrict__ h, const float* __restrict__ al_s,
    const float* __restrict__ al_d, const int* __restrict__ offs,
    const int* __restrict__ srcs, const float* __restrict__ bias,
    float* __restrict__ out_f32, unsigned short* __restrict__ out_b16, int relu) {
    int n = blockIdx.x;
    int t = threadIdx.x;
    int wave = t >> 6, lane = t & 63;
    int beg = offs[n], end = offs[n + 1];
    int deg = end - beg;

    __shared__ float alpha_sh[HH][MAXE];
    __shared__ int   srcs_sh[MAXE];
    __shared__ float m_s[HH], idn_s[HH], ald_sh[HH];

    // ---- phase 1: wave-parallel softmax, head = wave ----
    float ald = al_d[n * HH + wave];
    float m = -1e30f;
    for (int e = beg + lane; e < end; e += 64) {
        int s = srcs[e];
        if (wave == 0 && (e - beg) < MAXE) srcs_sh[e - beg] = s;
        float sc = al_s[s * HH + wave] + ald;
        sc = sc > 0.f ? sc : 0.2f * sc;
        m = fmaxf(m, sc);
    }
#pragma unroll
    for (int d = 32; d; d >>= 1) m = fmaxf(m, __shfl_xor(m, d));
    float den = 0.f;
    if (deg <= MAXE) {
        for (int e = beg + lane; e < end; e += 64) {
            int s = srcs[e];
            float sc = al_s[s * HH + wave] + ald;
            sc = sc > 0.f ? sc : 0.2f * sc;
            float ex = __expf(sc - m);
            den += ex;
            alpha_sh[wave][e - beg] = ex;
        }
    } else {
        for (int e = beg + lane; e < end; e += 64) {
            int s = srcs[e];
            float sc = al_s[s * HH + wave] + ald;
            sc = sc > 0.f ? sc : 0.2f * sc;
            den += __expf(sc - m);
        }
    }
#pragma unroll
    for (int d = 32; d; d >>= 1) den += __shfl_xor(den, d);
    float idn = 1.f / (den + 1e-16f);
    if (deg <= MAXE) {
        for (int e = beg + lane; e < end; e += 64)
            alpha_sh[wave][e - beg] *= idn;
    }
    if (lane == 0) { m_s[wave] = m; idn_s[wave] = idn; ald_sh[wave] = ald; }
    __syncthreads();

    // ---- phase 2: gather-aggregate ----
    int head = wave;
    float acc = 0.f;
    if (deg <= MAXE) {
#pragma unroll 4
        for (int j = 0; j < deg; ++j) {
            int s = srcs_sh[j];
            float a = alpha_sh[head][j];
            acc += a * h[(size_t)s * FF + t];
        }
    } else {
        float mm = m_s[head], iidn = idn_s[head], aald = ald_sh[head];
        for (int e = beg; e < end; ++e) {
            int s = srcs[e];
            float sc = al_s[s * HH + head] + aald;
            sc = sc > 0.f ? sc : 0.2f * sc;
            float a = __expf(sc - mm) * iidn;
            acc += a * h[(size_t)s * FF + t];
        }
    }
    float v = acc + bias[t];
    if (relu) v = fmaxf(v, 0.f);
    if (out_f32) out_f32[(size_t)n * FF + t] = v;
    if (out_b16) out_b16[(size_t)n * FF + t] = f2bf(v);
}

// ---------------- W2 -> W2^T bf16 (N x K) ----------------
__global__ void prep_w2t(const float* __restrict__ W2, unsigned short* __restrict__ W2T) {
    int i = blockIdx.x * blockDim.x + threadIdx.x;
    if (i >= FF * FF) return;
    int n = i >> 9, k = i & 511;
    W2T[i] = f2bf(W2[k * FF + n]);
}

// ---------------- bf16 MFMA GEMM: C[MP,N] = A[MP,K] @ BT[N,K]^T ----------------
// 128x128 tile, BK=64, 4 waves (2x2), each wave 64x64 (4x4 frags of 16x16x32).
// LDS linear [128][64] bf16; global source pre-swizzled (kc ^= row&7), reads
// apply the same XOR -> spread banks instead of 16-way conflict.
__global__ __launch_bounds__(256) void gemm_mfma(
    const unsigned short* __restrict__ A,   // [MP][K] bf16
    const unsigned short* __restrict__ BT,  // [N][K]  bf16
    float* __restrict__ C,                  // [MP][N] f32
    int N, int K) {
    __shared__ unsigned short As[128 * 64];
    __shared__ unsigned short Bs[128 * 64];
    int t = threadIdx.x;
    int wave = t >> 6, lane = t & 63;
    int wr = wave >> 1, wc = wave & 1;
    int m0 = blockIdx.x * 128, n0 = blockIdx.y * 128;

    f32x4 acc[4][4] = {};

    int kg = lane >> 4;         // 0..3 k-group for fragment reads
    int lr = lane & 15;

    for (int k0 = 0; k0 < K; k0 += 64) {
        // ---- stage A and B tiles (async, linear LDS dest, swizzled source) ----
#pragma unroll
        for (int q = 0; q < 4; ++q) {
            int c   = q * 256 + t;
            int row = c >> 3, kc = c & 7;
            int kcs = kc ^ (row & 7);
            const unsigned short* ga = A + (size_t)(m0 + row) * K + k0 + kcs * 8;
            const unsigned short* gb = BT + (size_t)(n0 + row) * K + k0 + kcs * 8;
            unsigned short* la = As + (size_t)(q * 256 + wave * 64) * 8;
            unsigned short* lb = Bs + (size_t)(q * 256 + wave * 64) * 8;
            __builtin_amdgcn_global_load_lds(
                (const __attribute__((address_space(1))) void*)ga,
                (__attribute__((address_space(3))) void*)la, 16, 0, 0);
            __builtin_amdgcn_global_load_lds(
                (const __attribute__((address_space(1))) void*)gb,
                (__attribute__((address_space(3))) void*)lb, 16, 0, 0);
        }
        __syncthreads();   // drains vmcnt before barrier -> LDS ready

        // ---- compute ----
#pragma unroll
        for (int ks = 0; ks < 2; ++ks) {
            bf16x8 af[4], bf[4];
#pragma unroll
            for (int i = 0; i < 4; ++i) {
                int rowa = wr * 64 + i * 16 + lr;
                af[i] = *(const bf16x8*)&As[rowa * 64 + (((ks << 2) | kg) ^ (rowa & 7)) * 8];
                int rowb = wc * 64 + i * 16 + lr;
                bf[i] = *(const bf16x8*)&Bs[rowb * 64 + (((ks << 2) | kg) ^ (rowb & 7)) * 8];
            }
#pragma unroll
            for (int i = 0; i < 4; ++i)
#pragma unroll
                for (int j = 0; j < 4; ++j)
                    acc[i][j] = __builtin_amdgcn_mfma_f32_16x16x32_bf16(
                        af[i], bf[j], acc[i][j], 0, 0, 0);
        }
        __syncthreads();   // all reads done before next stage overwrites
    }

    // ---- epilogue: C/D layout col=lane&15, row=(lane>>4)*4+reg ----
#pragma unroll
    for (int i = 0; i < 4; ++i) {
        int r = m0 + wr * 64 + i * 16 + kg * 4;
#pragma unroll
        for (int j = 0; j < 4; ++j) {
            int cc = n0 + wc * 64 + j * 16 + lr;
#pragma unroll
            for (int reg = 0; reg < 4; ++reg)
                C[(size_t)(r + reg) * N + cc] = acc[i][j][reg];
        }
    }
}

// ---------------- generic fp32 tiled GEMM (layer 3 only) ----------------
__global__ __launch_bounds__(256) void gemm_tiled(
    const float* __restrict__ A, const float* __restrict__ B, float* __restrict__ C,
    int M, int N, int K) {
    __shared__ float As[16][68];
    __shared__ float Bs[16][64];
    int tid = threadIdx.x;
    int tx = tid & 15, ty = tid >> 4;
    int m0 = blockIdx.x * 64, n0 = blockIdx.y * 64;
    float acc[4][4] = {};
    int arow = tid >> 2;
    int akq = (tid & 3) * 4;
    int bk  = tid >> 4;
    int bnq = (tid & 15) * 4;
    for (int k0 = 0; k0 < K; k0 += 16) {
        {
            int grow = m0 + arow;
            if (grow < M) {
                const float* p = &A[(size_t)grow * K + k0 + akq];
                float4 v = *(const float4*)p;
                As[akq + 0][arow] = v.x; As[akq + 1][arow] = v.y;
                As[akq + 2][arow] = v.z; As[akq + 3][arow] = v.w;
            } else {
                As[akq + 0][arow] = 0.f; As[akq + 1][arow] = 0.f;
                As[akq + 2][arow] = 0.f; As[akq + 3][arow] = 0.f;
            }
        }
        {
            int gn = n0 + bnq;
            const float* p = &B[(size_t)(k0 + bk) * N + gn];
            if (gn + 3 < N) {
                *(float4*)&Bs[bk][bnq] = *(const float4*)p;
            } else {
#pragma unroll
                for (int j = 0; j < 4; ++j)
                    Bs[bk][bnq + j] = (gn + j < N) ? p[j] : 0.f;
            }
        }
        __syncthreads();
#pragma unroll
        for (int k = 0; k < 16; ++k) {
            float4 a4 = *(const float4*)&As[k][ty * 4];
            float4 b4 = *(const float4*)&Bs[k][tx * 4];
            float av[4] = {a4.x, a4.y, a4.z, a4.w};
            float bv[4] = {b4.x, b4.y, b4.z, b4.w};
#pragma unroll
            for (int i = 0; i < 4; ++i)
#pragma unroll
                for (int j = 0; j < 4; ++j)
                    acc[i][j] += av[i] * bv[j];
        }
        __syncthreads();
    }
#pragma unroll
    for (int i = 0; i < 4; ++i) {
        int r = m0 + ty * 4 + i;
        if (r >= M) continue;
#pragma unroll
        for (int j = 0; j < 4; ++j) {
            int cidx = n0 + tx * 4 + j;
            if (cidx < N) C[(size_t)r * N + cidx] = acc[i][j];
        }
    }
}

// ---------------- layer-3 attention logits (F=40, C=5) ----------------
__global__ void al40_kernel(const float* __restrict__ h3, const float* __restrict__ as3,
                            const float* __restrict__ ad3, float* __restrict__ al_s,
                            float* __restrict__ al_d) {
    int n = blockIdx.x * blockDim.x + threadIdx.x;
    if (n >= NN) return;
#pragma unroll
    for (int hh = 0; hh < HH; ++hh) {
        float s = 0.f, d = 0.f;
#pragma unroll
        for (int c = 0; c < C3; ++c) {
            float v = h3[(size_t)n * F3 + hh * C3 + c];
            s += v * as3[hh * C3 + c];
            d += v * ad3[hh * C3 + c];
        }
        al_s[n * HH + hh] = s;
        al_d[n * HH + hh] = d;
    }
}

// ---------------- layer-3 attention + head-mean + bias + log_softmax ----------------
__global__ __launch_bounds__(64) void attn3_kernel(
    const float* __restrict__ h3, const float* __restrict__ al_s,
    const float* __restrict__ al_d, const int* __restrict__ offs,
    const int* __restrict__ srcs, const float* __restrict__ b3,
    float* __restrict__ out) {
    int n = blockIdx.x;
    int t = threadIdx.x;
    int beg = offs[n], end = offs[n + 1];
    __shared__ float m_s[HH], idn_s[HH], ald_sh[HH];
    __shared__ float accs[HH][C3];
    __shared__ float vv[C3];
    if (t < HH) ald_sh[t] = al_d[n * HH + t];
    __syncthreads();
    if (t < HH) {
        float ald = ald_sh[t];
        float m = -1e30f;
        for (int e = beg; e < end; ++e) {
            int s = srcs[e];
            float sc = al_s[s * HH + t] + ald;
            sc = sc > 0.f ? sc : 0.2f * sc;
            m = fmaxf(m, sc);
        }
        float den = 0.f;
        for (int e = beg; e < end; ++e) {
            int s = srcs[e];
            float sc = al_s[s * HH + t] + ald;
            sc = sc > 0.f ? sc : 0.2f * sc;
            den += __expf(sc - m);
        }
        m_s[t] = m;
        idn_s[t] = 1.f / (den + 1e-16f);
    }
    __syncthreads();
    if (t < F3) {
        int hh = t / C3;
        int c = t - hh * C3;
        float m = m_s[hh], idn = idn_s[hh], ald = ald_sh[hh];
        float acc = 0.f;
        for (int e = beg; e < end; ++e) {
            int s = srcs[e];
            float sc = al_s[s * HH + hh] + ald;
            sc = sc > 0.f ? sc : 0.2f * sc;
            float a = __expf(sc - m) * idn;
            acc += a * h3[(size_t)s * F3 + t];
        }
        accs[hh][c] = acc;
    }
    __syncthreads();
    if (t < C3) {
        float s = 0.f;
#pragma unroll
        for (int hh = 0; hh < HH; ++hh) s += accs[hh][t];
        vv[t] = s * 0.125f + b3[t];
    }
    __syncthreads();
    if (t < C3) {
        float mx = vv[0];
#pragma unroll
        for (int c = 1; c < C3; ++c) mx = fmaxf(mx, vv[c]);
        float se = 0.f;
#pragma unroll
        for (int c = 0; c < C3; ++c) se += __expf(vv[c] - mx);
        out[(size_t)n * C3 + t] = vv[t] - mx - logf(se);
    }
}

// ---------------- host launcher ----------------
extern "C" void kernel_launch(void* const* d_in, const int* in_sizes, int n_in,
                              void* d_out, int out_size, void* d_ws, size_t ws_size,
                              hipStream_t stream) {
    const float* x   = (const float*)d_in[0];
    const int*   ei  = (const int*)d_in[1];
    const float* W1  = (const float*)d_in[2];
    const float* as1 = (const float*)d_in[3];
    const float* ad1 = (const float*)d_in[4];
    const float* b1  = (const float*)d_in[5];
    const float* W2  = (const float*)d_in[6];
    const float* as2 = (const float*)d_in[7];
    const float* ad2 = (const float*)d_in[8];
    const float* b2  = (const float*)d_in[9];
    const float* W3  = (const float*)d_in[10];
    const float* as3 = (const float*)d_in[11];
    const float* ad3 = (const float*)d_in[12];
    const float* b3  = (const float*)d_in[13];
    float* out = (float*)d_out;

    // ---- workspace layout with lifetime aliasing (ws budget ~256MiB) ----
    // Abuf (fp32 h, MP rows): live all run.                          102.5 MB
    // region2: { Ab16 (51.2MB) + W2T (0.5MB) } dead after gemm_mfma;
    //          Bbuf (fp32, NN rows, 102.4MB) aliases them (written later).
    // h3 + logits + CSR follow region2.                       total ~218.4 MB
    auto au = [](size_t x) { return (x + 255) & ~(size_t)255; };
    char* p = (char*)d_ws;
    float* Abuf = (float*)p;              p += au((size_t)MP * FF * 4);
    char* r2 = p;
    unsigned short* Ab16 = (unsigned short*)r2;
    unsigned short* W2T  = (unsigned short*)(r2 + au((size_t)MP * FF * 2));
    float* Bbuf = (float*)r2;             // aliases Ab16+W2T (disjoint lifetimes)
    {
        size_t a = au((size_t)MP * FF * 2) + au((size_t)FF * FF * 2);
        size_t b = au((size_t)NN * FF * 4);
        p = r2 + (a > b ? a : b);
    }
    float* h3   = (float*)p;              p += au((size_t)NN * F3 * 4);
    float* alS  = (float*)p;              p += au((size_t)NN * HH * 4);
    float* alD  = (float*)p;              p += au((size_t)NN * HH * 4);
    int* offs   = (int*)p;                p += au((size_t)(NN + 1) * 4);
    int* cnt    = (int*)p;                p += au((size_t)NN * 4);
    int* srcs   = (int*)p;                p += au((size_t)ETOT * 4);

    // ---- CSR build (dst-sorted) + prep ----
    zero_int_kernel<<<(NN + 255) / 256, 256, 0, stream>>>(cnt, NN);
    count_kernel<<<(ETOT + 255) / 256, 256, 0, stream>>>(ei, cnt);
    scan_kernel<<<1, 1024, 0, stream>>>(cnt, offs, NN);
    zero_int_kernel<<<(NN + 255) / 256, 256, 0, stream>>>(cnt, NN);
    scatter_kernel<<<(ETOT + 255) / 256, 256, 0, stream>>>(ei, offs, cnt, srcs);
    zero_tail_kernel<<<((MP - NN) * FF + 255) / 256, 256, 0, stream>>>(Ab16);
    prep_w2t<<<(FF * FF + 255) / 256, 256, 0, stream>>>(W2, W2T);

    // ---- layer 1 ----
    gemm1_fused<<<NN, 512, 0, stream>>>(x, W1, as1, ad1, Abuf, alS, alD);
    attn512_kernel<<<NN, 512, 0, stream>>>(Abuf, alS, alD, offs, srcs, b1,
                                           nullptr, Ab16, 1);

    // ---- layer 2: bf16 MFMA GEMM (reads Ab16/W2T, writes Abuf) ----
    gemm_mfma<<<dim3(MP / 128, FF / 128), 256, 0, stream>>>(Ab16, W2T, Abuf, FF, FF);
    al512_kernel<<<NN, 512, 0, stream>>>(Abuf, as2, ad2, alS, alD);
    // Ab16/W2T now dead; Bbuf (same bytes) comes alive here:
    attn512_kernel<<<NN, 512, 0, stream>>>(Abuf, alS, alD, offs, srcs, b2,
                                           Bbuf, nullptr, 1);

    // ---- layer 3 ----
    gemm_tiled<<<dim3((NN + 63) / 64, 1), 256, 0, stream>>>(Bbuf, W3, h3, NN, F3, FF);
    al40_kernel<<<(NN + 255) / 256, 256, 0, stream>>>(h3, as3, ad3, alS, alD);
    attn3_kernel<<<NN, 64, 0, stream>>>(h3, alS, alD, offs, srcs, b3, out);
}

// Round 6
// 576.770 us; speedup vs baseline: 2.8259x; 1.5302x over previous
//
#include <hip/hip_runtime.h>
#include <hip/hip_bf16.h>

#define NN    50000   // nodes
#define MP    50048   // padded to 128*391 for MFMA GEMM
#define E0C   400000  // raw edges
#define ETOT  450000  // + self loops
#define HH    8
#define FF    512     // H*C layers 1-2
#define F3    40      // H*C3 layer 3
#define C3    5
#define MAXE  128     // LDS alpha-cache capacity (deg ~ Poisson(8)+1)

typedef __attribute__((ext_vector_type(8))) short bf16x8;
typedef __attribute__((ext_vector_type(8))) short s16x8;
typedef __attribute__((ext_vector_type(4))) float f32x4;

__device__ inline unsigned short f2bf(float f) {
    union { float f; unsigned int u; } v; v.f = f;
    unsigned int r = v.u + 0x7FFF + ((v.u >> 16) & 1);
    return (unsigned short)(r >> 16);
}
__device__ inline float bf2f(unsigned short u) {
    union { unsigned int i; float f; } v; v.i = ((unsigned int)u) << 16;
    return v.f;
}

// ---------------- utility ----------------
__global__ void zero_int_kernel(int* p, int n) {
    int i = blockIdx.x * blockDim.x + threadIdx.x;
    if (i < n) p[i] = 0;
}

__global__ void zero_tail_kernel(unsigned short* A2) {
    int i = blockIdx.x * blockDim.x + threadIdx.x;
    int total = (MP - NN) * FF;
    if (i < total) A2[(size_t)NN * FF + i] = 0;
}

// ---------------- CSR build ----------------
__global__ void count_kernel(const int* __restrict__ ei, int* __restrict__ cnt) {
    int e = blockIdx.x * blockDim.x + threadIdx.x;
    if (e >= ETOT) return;
    int dst = (e < E0C) ? ei[E0C + e] : (e - E0C);
    atomicAdd(&cnt[dst], 1);
}

__global__ __launch_bounds__(1024) void scan_kernel(const int* __restrict__ cnt,
                                                    int* __restrict__ offs, int n) {
    __shared__ int s[1024];
    __shared__ int carry_sh;
    int tid = threadIdx.x;
    if (tid == 0) carry_sh = 0;
    __syncthreads();
    for (int base = 0; base < n; base += 1024) {
        int i = base + tid;
        s[tid] = (i < n) ? cnt[i] : 0;
        __syncthreads();
        for (int d = 1; d < 1024; d <<= 1) {
            int add = (tid >= d) ? s[tid - d] : 0;
            __syncthreads();
            s[tid] += add;
            __syncthreads();
        }
        int c = carry_sh;
        if (i < n) offs[i + 1] = c + s[tid];
        __syncthreads();
        if (tid == 1023) carry_sh = c + s[1023];
        __syncthreads();
    }
    if (tid == 0) offs[0] = 0;
}

__global__ void scatter_kernel(const int* __restrict__ ei, const int* __restrict__ offs,
                               int* __restrict__ cur, int* __restrict__ srcs) {
    int e = blockIdx.x * blockDim.x + threadIdx.x;
    if (e >= ETOT) return;
    int src, dst;
    if (e < E0C) { src = ei[e]; dst = ei[E0C + e]; }
    else         { src = dst = e - E0C; }
    int pos = offs[dst] + atomicAdd(&cur[dst], 1);
    srcs[pos] = src;
}

// ---------------- layer 1 GEMM (K=12) fused with attention logits ----------------
// writes h as bf16 (gather source); logits computed from fp32 acc.
__global__ __launch_bounds__(512) void gemm1_fused(
    const float* __restrict__ x, const float* __restrict__ W1,
    const float* __restrict__ as1, const float* __restrict__ ad1,
    unsigned short* __restrict__ hb, float* __restrict__ al_s, float* __restrict__ al_d) {
    int n = blockIdx.x;
    int t = threadIdx.x;
    __shared__ float xs[12];
    if (t < 12) xs[t] = x[n * 12 + t];
    __syncthreads();
    float acc = 0.f;
#pragma unroll
    for (int k = 0; k < 12; ++k) acc += xs[k] * W1[k * FF + t];
    hb[(size_t)n * FF + t] = f2bf(acc);
    int head = t >> 6;
    float ps = acc * as1[t];
    float pd = acc * ad1[t];
#pragma unroll
    for (int d = 32; d; d >>= 1) {
        ps += __shfl_down(ps, d);
        pd += __shfl_down(pd, d);
    }
    if ((t & 63) == 0) {
        al_s[n * HH + head] = ps;
        al_d[n * HH + head] = pd;
    }
}

// ---------------- attention aggregate: ONE WAVE PER NODE, bf16 gather ----------
// 4 waves/block, each wave owns one node. Lane layout phase1: h=lane>>3,
// es=lane&7 (8 lanes per head). Phase2: lane owns features lane*8..+7, all in
// head lane>>3 (same grouping). bf16x8 load = whole 1KB row per wave-instr.
__global__ __launch_bounds__(256) void attn_gather(
    const unsigned short* __restrict__ Hb,   // [*,FF] bf16
    const float* __restrict__ alS, const float* __restrict__ alD,
    const int* __restrict__ offs, const int* __restrict__ srcs,
    const float* __restrict__ bias,
    float* __restrict__ out_f32, unsigned short* __restrict__ out_b16, int relu) {
    __shared__ float alpha_sh[4][MAXE][HH];
    __shared__ int   srcs_sh[4][MAXE];
    int w = threadIdx.x >> 6, lane = threadIdx.x & 63;
    int n = blockIdx.x * 4 + w;
    if (n >= NN) return;
    int h = lane >> 3, es = lane & 7;
    int beg = offs[n], end = offs[n + 1], deg = end - beg;

    float ald = alD[n * HH + h];
    // pass 1: per-head max (8 lanes per head, strided edges)
    float m = -1e30f;
    for (int e = es; e < deg; e += 8) {
        int s = srcs[beg + e];
        float sc = alS[s * HH + h] + ald;
        sc = sc > 0.f ? sc : 0.2f * sc;
        m = fmaxf(m, sc);
    }
    m = fmaxf(m, __shfl_xor(m, 1));
    m = fmaxf(m, __shfl_xor(m, 2));
    m = fmaxf(m, __shfl_xor(m, 4));
    // pass 2: exp + denom, stash alpha/srcs in LDS
    float den = 0.f;
    for (int e = es; e < deg; e += 8) {
        int s = srcs[beg + e];
        if (h == 0 && e < MAXE) srcs_sh[w][e] = s;
        float sc = alS[s * HH + h] + ald;
        sc = sc > 0.f ? sc : 0.2f * sc;
        float ex = __expf(sc - m);
        den += ex;
        if (e < MAXE) alpha_sh[w][e][h] = ex;
    }
    den += __shfl_xor(den, 1);
    den += __shfl_xor(den, 2);
    den += __shfl_xor(den, 4);
    float idn = 1.f / (den + 1e-16f);
    int cap = deg < MAXE ? deg : MAXE;
    for (int e = es; e < cap; e += 8) alpha_sh[w][e][h] *= idn;

    // phase 2: gather (lane feature block f0..f0+7, head h)
    int f0 = lane * 8;
    float acc[8] = {};
    if (deg <= MAXE) {
        for (int e = 0; e < deg; ++e) {
            int s = srcs_sh[w][e];
            float a = alpha_sh[w][e][h];
            bf16x8 v = *(const bf16x8*)&Hb[(size_t)s * FF + f0];
#pragma unroll
            for (int k = 0; k < 8; ++k)
                acc[k] += a * bf2f((unsigned short)v[k]);
        }
    } else {
        for (int e = 0; e < deg; ++e) {
            int s = srcs[beg + e];
            float sc = alS[s * HH + h] + ald;
            sc = sc > 0.f ? sc : 0.2f * sc;
            float a = __expf(sc - m) * idn;
            bf16x8 v = *(const bf16x8*)&Hb[(size_t)s * FF + f0];
#pragma unroll
            for (int k = 0; k < 8; ++k)
                acc[k] += a * bf2f((unsigned short)v[k]);
        }
    }
    float4 b0 = *(const float4*)&bias[f0];
    float4 b1 = *(const float4*)&bias[f0 + 4];
    float bv[8] = {b0.x, b0.y, b0.z, b0.w, b1.x, b1.y, b1.z, b1.w};
    float vv[8];
#pragma unroll
    for (int k = 0; k < 8; ++k) {
        float t = acc[k] + bv[k];
        vv[k] = relu ? fmaxf(t, 0.f) : t;
    }
    if (out_f32) {
        float4 o0 = {vv[0], vv[1], vv[2], vv[3]};
        float4 o1 = {vv[4], vv[5], vv[6], vv[7]};
        *(float4*)&out_f32[(size_t)n * FF + f0] = o0;
        *(float4*)&out_f32[(size_t)n * FF + f0 + 4] = o1;
    }
    if (out_b16) {
        s16x8 ov;
#pragma unroll
        for (int k = 0; k < 8; ++k) ov[k] = (short)f2bf(vv[k]);
        *(s16x8*)&out_b16[(size_t)n * FF + f0] = ov;
    }
}

// ---------------- W2 -> W2^T bf16 (N x K) ----------------
__global__ void prep_w2t(const float* __restrict__ W2, unsigned short* __restrict__ W2T) {
    int i = blockIdx.x * blockDim.x + threadIdx.x;
    if (i >= FF * FF) return;
    int n = i >> 9, k = i & 511;
    W2T[i] = f2bf(W2[k * FF + n]);
}

// ---------------- bf16 MFMA GEMM + fused logits, bf16 output ----------------
// C[MP,N] = A[MP,K] @ BT[N,K]^T ; writes Cb (bf16) and alS/alD (per row, head).
// Each (row, head) has exactly one writer wave -> plain stores, no atomics.
__global__ __launch_bounds__(256) void gemm_mfma(
    const unsigned short* __restrict__ A,   // [MP][K] bf16
    const unsigned short* __restrict__ BT,  // [N][K]  bf16
    const float* __restrict__ a_s, const float* __restrict__ a_d,  // [N]
    unsigned short* __restrict__ Cb,        // [MP][N] bf16
    float* __restrict__ alS, float* __restrict__ alD,              // [MP][HH]
    int N, int K) {
    __shared__ unsigned short As[128 * 64];
    __shared__ unsigned short Bs[128 * 64];
    int t = threadIdx.x;
    int wave = t >> 6, lane = t & 63;
    int wr = wave >> 1, wc = wave & 1;
    int m0 = blockIdx.x * 128, n0 = blockIdx.y * 128;

    f32x4 acc[4][4] = {};
    int kg = lane >> 4;         // 0..3
    int lr = lane & 15;

    for (int k0 = 0; k0 < K; k0 += 64) {
#pragma unroll
        for (int q = 0; q < 4; ++q) {
            int c   = q * 256 + t;
            int row = c >> 3, kc = c & 7;
            int kcs = kc ^ (row & 7);
            const unsigned short* ga = A + (size_t)(m0 + row) * K + k0 + kcs * 8;
            const unsigned short* gb = BT + (size_t)(n0 + row) * K + k0 + kcs * 8;
            unsigned short* la = As + (size_t)(q * 256 + wave * 64) * 8;
            unsigned short* lb = Bs + (size_t)(q * 256 + wave * 64) * 8;
            __builtin_amdgcn_global_load_lds(
                (const __attribute__((address_space(1))) void*)ga,
                (__attribute__((address_space(3))) void*)la, 16, 0, 0);
            __builtin_amdgcn_global_load_lds(
                (const __attribute__((address_space(1))) void*)gb,
                (__attribute__((address_space(3))) void*)lb, 16, 0, 0);
        }
        __syncthreads();
#pragma unroll
        for (int ks = 0; ks < 2; ++ks) {
            bf16x8 af[4], bf[4];
#pragma unroll
            for (int i = 0; i < 4; ++i) {
                int rowa = wr * 64 + i * 16 + lr;
                af[i] = *(const bf16x8*)&As[rowa * 64 + (((ks << 2) | kg) ^ (rowa & 7)) * 8];
                int rowb = wc * 64 + i * 16 + lr;
                bf[i] = *(const bf16x8*)&Bs[rowb * 64 + (((ks << 2) | kg) ^ (rowb & 7)) * 8];
            }
#pragma unroll
            for (int i = 0; i < 4; ++i)
#pragma unroll
                for (int j = 0; j < 4; ++j)
                    acc[i][j] = __builtin_amdgcn_mfma_f32_16x16x32_bf16(
                        af[i], bf[j], acc[i][j], 0, 0, 0);
        }
        __syncthreads();
    }

    // ---- fused attention logits: head = n0/64 + wc (one per wave) ----
    int head = (n0 >> 6) + wc;
    float asv[4], adv[4];
#pragma unroll
    for (int j = 0; j < 4; ++j) {
        int cc = n0 + wc * 64 + j * 16 + lr;
        asv[j] = a_s[cc];
        adv[j] = a_d[cc];
    }
#pragma unroll
    for (int i = 0; i < 4; ++i) {
#pragma unroll
        for (int reg = 0; reg < 4; ++reg) {
            float ps = 0.f, pd = 0.f;
#pragma unroll
            for (int j = 0; j < 4; ++j) {
                ps += acc[i][j][reg] * asv[j];
                pd += acc[i][j][reg] * adv[j];
            }
#pragma unroll
            for (int d = 1; d < 16; d <<= 1) {
                ps += __shfl_xor(ps, d);
                pd += __shfl_xor(pd, d);
            }
            if (lr == 0) {
                int r = m0 + wr * 64 + i * 16 + kg * 4 + reg;
                alS[(size_t)r * HH + head] = ps;
                alD[(size_t)r * HH + head] = pd;
            }
        }
    }

    // ---- bf16 C store: col=lane&15, row=kg*4+reg ----
#pragma unroll
    for (int i = 0; i < 4; ++i) {
        int rb = m0 + wr * 64 + i * 16 + kg * 4;
#pragma unroll
        for (int j = 0; j < 4; ++j) {
            int cc = n0 + wc * 64 + j * 16 + lr;
#pragma unroll
            for (int reg = 0; reg < 4; ++reg)
                Cb[(size_t)(rb + reg) * N + cc] = f2bf(acc[i][j][reg]);
        }
    }
}

// ---------------- generic fp32 tiled GEMM (layer 3 only) ----------------
__global__ __launch_bounds__(256) void gemm_tiled(
    const float* __restrict__ A, const float* __restrict__ B, float* __restrict__ C,
    int M, int N, int K) {
    __shared__ float As[16][68];
    __shared__ float Bs[16][64];
    int tid = threadIdx.x;
    int tx = tid & 15, ty = tid >> 4;
    int m0 = blockIdx.x * 64, n0 = blockIdx.y * 64;
    float acc[4][4] = {};
    int arow = tid >> 2;
    int akq = (tid & 3) * 4;
    int bk  = tid >> 4;
    int bnq = (tid & 15) * 4;
    for (int k0 = 0; k0 < K; k0 += 16) {
        {
            int grow = m0 + arow;
            if (grow < M) {
                const float* p = &A[(size_t)grow * K + k0 + akq];
                float4 v = *(const float4*)p;
                As[akq + 0][arow] = v.x; As[akq + 1][arow] = v.y;
                As[akq + 2][arow] = v.z; As[akq + 3][arow] = v.w;
            } else {
                As[akq + 0][arow] = 0.f; As[akq + 1][arow] = 0.f;
                As[akq + 2][arow] = 0.f; As[akq + 3][arow] = 0.f;
            }
        }
        {
            int gn = n0 + bnq;
            const float* p = &B[(size_t)(k0 + bk) * N + gn];
            if (gn + 3 < N) {
                *(float4*)&Bs[bk][bnq] = *(const float4*)p;
            } else {
#pragma unroll
                for (int j = 0; j < 4; ++j)
                    Bs[bk][bnq + j] = (gn + j < N) ? p[j] : 0.f;
            }
        }
        __syncthreads();
#pragma unroll
        for (int k = 0; k < 16; ++k) {
            float4 a4 = *(const float4*)&As[k][ty * 4];
            float4 b4 = *(const float4*)&Bs[k][tx * 4];
            float av[4] = {a4.x, a4.y, a4.z, a4.w};
            float bv[4] = {b4.x, b4.y, b4.z, b4.w};
#pragma unroll
            for (int i = 0; i < 4; ++i)
#pragma unroll
                for (int j = 0; j < 4; ++j)
                    acc[i][j] += av[i] * bv[j];
        }
        __syncthreads();
    }
#pragma unroll
    for (int i = 0; i < 4; ++i) {
        int r = m0 + ty * 4 + i;
        if (r >= M) continue;
#pragma unroll
        for (int j = 0; j < 4; ++j) {
            int cidx = n0 + tx * 4 + j;
            if (cidx < N) C[(size_t)r * N + cidx] = acc[i][j];
        }
    }
}

// ---------------- layer-3 attention logits (F=40, C=5) ----------------
__global__ void al40_kernel(const float* __restrict__ h3, const float* __restrict__ as3,
                            const float* __restrict__ ad3, float* __restrict__ al_s,
                            float* __restrict__ al_d) {
    int n = blockIdx.x * blockDim.x + threadIdx.x;
    if (n >= NN) return;
#pragma unroll
    for (int hh = 0; hh < HH; ++hh) {
        float s = 0.f, d = 0.f;
#pragma unroll
        for (int c = 0; c < C3; ++c) {
            float v = h3[(size_t)n * F3 + hh * C3 + c];
            s += v * as3[hh * C3 + c];
            d += v * ad3[hh * C3 + c];
        }
        al_s[n * HH + hh] = s;
        al_d[n * HH + hh] = d;
    }
}

// ---------------- layer-3 attention + head-mean + bias + log_softmax ----------------
__global__ __launch_bounds__(64) void attn3_kernel(
    const float* __restrict__ h3, const float* __restrict__ al_s,
    const float* __restrict__ al_d, const int* __restrict__ offs,
    const int* __restrict__ srcs, const float* __restrict__ b3,
    float* __restrict__ out) {
    int n = blockIdx.x;
    int t = threadIdx.x;
    int beg = offs[n], end = offs[n + 1];
    __shared__ float m_s[HH], idn_s[HH], ald_sh[HH];
    __shared__ float accs[HH][C3];
    __shared__ float vv[C3];
    if (t < HH) ald_sh[t] = al_d[n * HH + t];
    __syncthreads();
    if (t < HH) {
        float ald = ald_sh[t];
        float m = -1e30f;
        for (int e = beg; e < end; ++e) {
            int s = srcs[e];
            float sc = al_s[s * HH + t] + ald;
            sc = sc > 0.f ? sc : 0.2f * sc;
            m = fmaxf(m, sc);
        }
        float den = 0.f;
        for (int e = beg; e < end; ++e) {
            int s = srcs[e];
            float sc = al_s[s * HH + t] + ald;
            sc = sc > 0.f ? sc : 0.2f * sc;
            den += __expf(sc - m);
        }
        m_s[t] = m;
        idn_s[t] = 1.f / (den + 1e-16f);
    }
    __syncthreads();
    if (t < F3) {
        int hh = t / C3;
        int c = t - hh * C3;
        float m = m_s[hh], idn = idn_s[hh], ald = ald_sh[hh];
        float acc = 0.f;
        for (int e = beg; e < end; ++e) {
            int s = srcs[e];
            float sc = al_s[s * HH + hh] + ald;
            sc = sc > 0.f ? sc : 0.2f * sc;
            float a = __expf(sc - m) * idn;
            acc += a * h3[(size_t)s * F3 + t];
        }
        accs[hh][c] = acc;
    }
    __syncthreads();
    if (t < C3) {
        float s = 0.f;
#pragma unroll
        for (int hh = 0; hh < HH; ++hh) s += accs[hh][t];
        vv[t] = s * 0.125f + b3[t];
    }
    __syncthreads();
    if (t < C3) {
        float mx = vv[0];
#pragma unroll
        for (int c = 1; c < C3; ++c) mx = fmaxf(mx, vv[c]);
        float se = 0.f;
#pragma unroll
        for (int c = 0; c < C3; ++c) se += __expf(vv[c] - mx);
        out[(size_t)n * C3 + t] = vv[t] - mx - logf(se);
    }
}

// ---------------- host launcher ----------------
extern "C" void kernel_launch(void* const* d_in, const int* in_sizes, int n_in,
                              void* d_out, int out_size, void* d_ws, size_t ws_size,
                              hipStream_t stream) {
    const float* x   = (const float*)d_in[0];
    const int*   ei  = (const int*)d_in[1];
    const float* W1  = (const float*)d_in[2];
    const float* as1 = (const float*)d_in[3];
    const float* ad1 = (const float*)d_in[4];
    const float* b1  = (const float*)d_in[5];
    const float* W2  = (const float*)d_in[6];
    const float* as2 = (const float*)d_in[7];
    const float* ad2 = (const float*)d_in[8];
    const float* b2  = (const float*)d_in[9];
    const float* W3  = (const float*)d_in[10];
    const float* as3 = (const float*)d_in[11];
    const float* ad3 = (const float*)d_in[12];
    const float* b3  = (const float*)d_in[13];
    float* out = (float*)d_out;

    // ---- workspace layout (lifetime-aliased, total ~167 MB) ----
    // R1: Hb1 (layer1 h bf16, dead after attn1)  ->  Hb2 (layer2 h bf16)
    // R2: A2 (attn1 out bf16) + W2T (dead after gemm_mfma) -> Bbuf (fp32)
    auto au = [](size_t v) { return (v + 255) & ~(size_t)255; };
    char* p = (char*)d_ws;
    size_t szHb = au((size_t)MP * FF * 2);           // 51.25 MB
    char* r1 = p;                                    // R1
    unsigned short* Hb1 = (unsigned short*)r1;
    unsigned short* Hb2 = (unsigned short*)r1;
    p += szHb;
    char* r2 = p;                                    // R2
    unsigned short* A2  = (unsigned short*)r2;
    unsigned short* W2T = (unsigned short*)(r2 + szHb);
    float* Bbuf = (float*)r2;
    {
        size_t a = szHb + au((size_t)FF * FF * 2);
        size_t b = au((size_t)NN * FF * 4);
        p = r2 + (a > b ? a : b);
    }
    float* alS  = (float*)p;  p += au((size_t)MP * HH * 4);
    float* alD  = (float*)p;  p += au((size_t)MP * HH * 4);
    float* h3   = (float*)p;  p += au((size_t)NN * F3 * 4);
    int* offs   = (int*)p;    p += au((size_t)(NN + 1) * 4);
    int* cnt    = (int*)p;    p += au((size_t)NN * 4);
    int* srcs   = (int*)p;    p += au((size_t)ETOT * 4);

    // ---- CSR build (dst-sorted) + prep ----
    zero_int_kernel<<<(NN + 255) / 256, 256, 0, stream>>>(cnt, NN);
    count_kernel<<<(ETOT + 255) / 256, 256, 0, stream>>>(ei, cnt);
    scan_kernel<<<1, 1024, 0, stream>>>(cnt, offs, NN);
    zero_int_kernel<<<(NN + 255) / 256, 256, 0, stream>>>(cnt, NN);
    scatter_kernel<<<(ETOT + 255) / 256, 256, 0, stream>>>(ei, offs, cnt, srcs);
    zero_tail_kernel<<<((MP - NN) * FF + 255) / 256, 256, 0, stream>>>(A2);
    prep_w2t<<<(FF * FF + 255) / 256, 256, 0, stream>>>(W2, W2T);

    // ---- layer 1 ----
    gemm1_fused<<<NN, 512, 0, stream>>>(x, W1, as1, ad1, Hb1, alS, alD);
    attn_gather<<<(NN + 3) / 4, 256, 0, stream>>>(Hb1, alS, alD, offs, srcs, b1,
                                                  nullptr, A2, 1);

    // ---- layer 2: bf16 MFMA GEMM (+ fused logits) ----
    gemm_mfma<<<dim3(MP / 128, FF / 128), 256, 0, stream>>>(
        A2, W2T, as2, ad2, Hb2, alS, alD, FF, FF);
    attn_gather<<<(NN + 3) / 4, 256, 0, stream>>>(Hb2, alS, alD, offs, srcs, b2,
                                                  Bbuf, nullptr, 1);

    // ---- layer 3 ----
    gemm_tiled<<<dim3((NN + 63) / 64, 1), 256, 0, stream>>>(Bbuf, W3, h3, NN, F3, FF);
    al40_kernel<<<(NN + 255) / 256, 256, 0, stream>>>(h3, as3, ad3, alS, alD);
    attn3_kernel<<<NN, 64, 0, stream>>>(h3, alS, alD, offs, srcs, b3, out);
}

// Round 7
// 464.431 us; speedup vs baseline: 3.5094x; 1.2419x over previous
//
#include <hip/hip_runtime.h>
#include <hip/hip_bf16.h>

#define NN    50000   // nodes
#define MP    50048   // padded to 128*391 for MFMA GEMM
#define E0C   400000  // raw edges
#define ETOT  450000  // + self loops
#define HH    8
#define FF    512     // H*C layers 1-2
#define F3    40      // H*C3 layer 3
#define C3    5
#define MAXE  128     // LDS alpha-cache capacity (deg ~ Poisson(8)+1)
#define NBLK  ((NN + 1023) / 1024)   // 49 scan blocks

typedef __attribute__((ext_vector_type(8))) short bf16x8;
typedef __attribute__((ext_vector_type(8))) short s16x8;
typedef __attribute__((ext_vector_type(4))) float f32x4;

__device__ inline unsigned short f2bf(float f) {
    union { float f; unsigned int u; } v; v.f = f;
    unsigned int r = v.u + 0x7FFF + ((v.u >> 16) & 1);
    return (unsigned short)(r >> 16);
}
__device__ inline float bf2f(unsigned short u) {
    union { unsigned int i; float f; } v; v.i = ((unsigned int)u) << 16;
    return v.f;
}

// ---------------- utility ----------------
__global__ void zero_int_kernel(int* p, int n) {
    int i = blockIdx.x * blockDim.x + threadIdx.x;
    if (i < n) p[i] = 0;
}

__global__ void zero_tail_kernel(unsigned short* A2) {
    int i = blockIdx.x * blockDim.x + threadIdx.x;
    int total = (MP - NN) * FF;
    if (i < total) A2[(size_t)NN * FF + i] = 0;
}

// ---------------- CSR build ----------------
__global__ void count_kernel(const int* __restrict__ ei, int* __restrict__ cnt) {
    int e = blockIdx.x * blockDim.x + threadIdx.x;
    if (e >= ETOT) return;
    int dst = (e < E0C) ? ei[E0C + e] : (e - E0C);
    atomicAdd(&cnt[dst], 1);
}

// 3-kernel parallel scan: per-block Hillis-Steele -> wave scan of sums -> add.
__global__ __launch_bounds__(1024) void scan_blocks(const int* __restrict__ cnt,
                                                    int* __restrict__ offs,
                                                    int* __restrict__ bsum) {
    __shared__ int s[1024];
    int tid = threadIdx.x;
    int i = blockIdx.x * 1024 + tid;
    s[tid] = (i < NN) ? cnt[i] : 0;
    __syncthreads();
    for (int d = 1; d < 1024; d <<= 1) {
        int add = (tid >= d) ? s[tid - d] : 0;
        __syncthreads();
        s[tid] += add;
        __syncthreads();
    }
    if (i < NN) offs[i + 1] = s[tid];
    if (tid == 1023) bsum[blockIdx.x] = s[1023];
}

__global__ __launch_bounds__(64) void scan_sums(int* __restrict__ bsum) {
    int lane = threadIdx.x;
    int v = (lane < NBLK) ? bsum[lane] : 0;
    int orig = v;
#pragma unroll
    for (int d = 1; d < 64; d <<= 1) {
        int o = __shfl_up(v, d);
        if (lane >= d) v += o;
    }
    if (lane < NBLK) bsum[lane] = v - orig;   // exclusive prefix
}

__global__ __launch_bounds__(1024) void scan_add(int* __restrict__ offs,
                                                 const int* __restrict__ bsum) {
    int i = blockIdx.x * 1024 + threadIdx.x;
    if (i < NN) offs[i + 1] += bsum[blockIdx.x];
    if (i == 0) offs[0] = 0;
}

__global__ void scatter_kernel(const int* __restrict__ ei, const int* __restrict__ offs,
                               int* __restrict__ cur, int* __restrict__ srcs) {
    int e = blockIdx.x * blockDim.x + threadIdx.x;
    if (e >= ETOT) return;
    int src, dst;
    if (e < E0C) { src = ei[e]; dst = ei[E0C + e]; }
    else         { src = dst = e - E0C; }
    int pos = offs[dst] + atomicAdd(&cur[dst], 1);
    srcs[pos] = src;
}

// ---------------- layer 1 GEMM (K=12) fused with logits, 64 nodes/block ------
// thread t owns features 2t,2t+1: W1 columns live in 24 registers (loaded once
// per block), x rows staged in LDS. Per node: 24 FMA + packed bf16 dword store
// + 32-lane shfl reduce for the head logits.
__global__ __launch_bounds__(256) void gemm1_fused(
    const float* __restrict__ x, const float* __restrict__ W1,
    const float* __restrict__ as1, const float* __restrict__ ad1,
    unsigned short* __restrict__ hb, float* __restrict__ al_s,
    float* __restrict__ al_d) {
    __shared__ float xs[64 * 12];
    int t = threadIdx.x;
    int n0 = blockIdx.x * 64;
    int nvalid = NN - n0; if (nvalid > 64) nvalid = 64;

    for (int j = t; j < nvalid * 12; j += 256) xs[j] = x[(size_t)n0 * 12 + j];
    __syncthreads();

    int f = t * 2;
    float w0[12], w1[12];
#pragma unroll
    for (int k = 0; k < 12; ++k) {
        float2 wv = *(const float2*)&W1[k * FF + f];
        w0[k] = wv.x; w1[k] = wv.y;
    }
    float2 asv = *(const float2*)&as1[f];
    float2 adv = *(const float2*)&ad1[f];
    int head = t >> 5;

    for (int ni = 0; ni < nvalid; ++ni) {
        const float* xp = &xs[ni * 12];
        float4 xa = *(const float4*)xp;
        float4 xb = *(const float4*)(xp + 4);
        float4 xc = *(const float4*)(xp + 8);
        float xv[12] = {xa.x, xa.y, xa.z, xa.w, xb.x, xb.y, xb.z, xb.w,
                        xc.x, xc.y, xc.z, xc.w};
        float h0 = 0.f, h1 = 0.f;
#pragma unroll
        for (int k = 0; k < 12; ++k) { h0 += xv[k] * w0[k]; h1 += xv[k] * w1[k]; }
        unsigned int u = ((unsigned int)f2bf(h1) << 16) | f2bf(h0);
        *(unsigned int*)&hb[(size_t)(n0 + ni) * FF + f] = u;
        float ps = h0 * asv.x + h1 * asv.y;
        float pd = h0 * adv.x + h1 * adv.y;
#pragma unroll
        for (int d = 1; d < 32; d <<= 1) {
            ps += __shfl_xor(ps, d);
            pd += __shfl_xor(pd, d);
        }
        if ((t & 31) == 0) {
            al_s[(size_t)(n0 + ni) * HH + head] = ps;
            al_d[(size_t)(n0 + ni) * HH + head] = pd;
        }
    }
}

// ---------------- attention aggregate: ONE WAVE PER NODE, bf16 gather ----------
__global__ __launch_bounds__(256) void attn_gather(
    const unsigned short* __restrict__ Hb,   // [*,FF] bf16
    const float* __restrict__ alS, const float* __restrict__ alD,
    const int* __restrict__ offs, const int* __restrict__ srcs,
    const float* __restrict__ bias,
    float* __restrict__ out_f32, unsigned short* __restrict__ out_b16, int relu) {
    __shared__ float alpha_sh[4][MAXE][HH];
    __shared__ int   srcs_sh[4][MAXE];
    int w = threadIdx.x >> 6, lane = threadIdx.x & 63;
    int n = blockIdx.x * 4 + w;
    if (n >= NN) return;
    int h = lane >> 3, es = lane & 7;
    int beg = offs[n], end = offs[n + 1], deg = end - beg;

    float ald = alD[n * HH + h];
    float m = -1e30f;
    for (int e = es; e < deg; e += 8) {
        int s = srcs[beg + e];
        float sc = alS[s * HH + h] + ald;
        sc = sc > 0.f ? sc : 0.2f * sc;
        m = fmaxf(m, sc);
    }
    m = fmaxf(m, __shfl_xor(m, 1));
    m = fmaxf(m, __shfl_xor(m, 2));
    m = fmaxf(m, __shfl_xor(m, 4));
    float den = 0.f;
    for (int e = es; e < deg; e += 8) {
        int s = srcs[beg + e];
        if (h == 0 && e < MAXE) srcs_sh[w][e] = s;
        float sc = alS[s * HH + h] + ald;
        sc = sc > 0.f ? sc : 0.2f * sc;
        float ex = __expf(sc - m);
        den += ex;
        if (e < MAXE) alpha_sh[w][e][h] = ex;
    }
    den += __shfl_xor(den, 1);
    den += __shfl_xor(den, 2);
    den += __shfl_xor(den, 4);
    float idn = 1.f / (den + 1e-16f);
    int cap = deg < MAXE ? deg : MAXE;
    for (int e = es; e < cap; e += 8) alpha_sh[w][e][h] *= idn;

    int f0 = lane * 8;
    float acc[8] = {};
    if (deg <= MAXE) {
        for (int e = 0; e < deg; ++e) {
            int s = srcs_sh[w][e];
            float a = alpha_sh[w][e][h];
            bf16x8 v = *(const bf16x8*)&Hb[(size_t)s * FF + f0];
#pragma unroll
            for (int k = 0; k < 8; ++k)
                acc[k] += a * bf2f((unsigned short)v[k]);
        }
    } else {
        for (int e = 0; e < deg; ++e) {
            int s = srcs[beg + e];
            float sc = alS[s * HH + h] + ald;
            sc = sc > 0.f ? sc : 0.2f * sc;
            float a = __expf(sc - m) * idn;
            bf16x8 v = *(const bf16x8*)&Hb[(size_t)s * FF + f0];
#pragma unroll
            for (int k = 0; k < 8; ++k)
                acc[k] += a * bf2f((unsigned short)v[k]);
        }
    }
    float4 b0 = *(const float4*)&bias[f0];
    float4 b1 = *(const float4*)&bias[f0 + 4];
    float bv[8] = {b0.x, b0.y, b0.z, b0.w, b1.x, b1.y, b1.z, b1.w};
    float vv[8];
#pragma unroll
    for (int k = 0; k < 8; ++k) {
        float t = acc[k] + bv[k];
        vv[k] = relu ? fmaxf(t, 0.f) : t;
    }
    if (out_f32) {
        float4 o0 = {vv[0], vv[1], vv[2], vv[3]};
        float4 o1 = {vv[4], vv[5], vv[6], vv[7]};
        *(float4*)&out_f32[(size_t)n * FF + f0] = o0;
        *(float4*)&out_f32[(size_t)n * FF + f0 + 4] = o1;
    }
    if (out_b16) {
        s16x8 ov;
#pragma unroll
        for (int k = 0; k < 8; ++k) ov[k] = (short)f2bf(vv[k]);
        *(s16x8*)&out_b16[(size_t)n * FF + f0] = ov;
    }
}

// ---------------- W2 -> W2^T bf16 (N x K) ----------------
__global__ void prep_w2t(const float* __restrict__ W2, unsigned short* __restrict__ W2T) {
    int i = blockIdx.x * blockDim.x + threadIdx.x;
    if (i >= FF * FF) return;
    int n = i >> 9, k = i & 511;
    W2T[i] = f2bf(W2[k * FF + n]);
}

// ---------------- bf16 MFMA GEMM + fused logits, bf16 output ----------------
__global__ __launch_bounds__(256) void gemm_mfma(
    const unsigned short* __restrict__ A,   // [MP][K] bf16
    const unsigned short* __restrict__ BT,  // [N][K]  bf16
    const float* __restrict__ a_s, const float* __restrict__ a_d,  // [N]
    unsigned short* __restrict__ Cb,        // [MP][N] bf16
    float* __restrict__ alS, float* __restrict__ alD,              // [MP][HH]
    int N, int K) {
    __shared__ unsigned short As[128 * 64];
    __shared__ unsigned short Bs[128 * 64];
    int t = threadIdx.x;
    int wave = t >> 6, lane = t & 63;
    int wr = wave >> 1, wc = wave & 1;
    int m0 = blockIdx.x * 128, n0 = blockIdx.y * 128;

    f32x4 acc[4][4] = {};
    int kg = lane >> 4;
    int lr = lane & 15;

    for (int k0 = 0; k0 < K; k0 += 64) {
#pragma unroll
        for (int q = 0; q < 4; ++q) {
            int c   = q * 256 + t;
            int row = c >> 3, kc = c & 7;
            int kcs = kc ^ (row & 7);
            const unsigned short* ga = A + (size_t)(m0 + row) * K + k0 + kcs * 8;
            const unsigned short* gb = BT + (size_t)(n0 + row) * K + k0 + kcs * 8;
            unsigned short* la = As + (size_t)(q * 256 + wave * 64) * 8;
            unsigned short* lb = Bs + (size_t)(q * 256 + wave * 64) * 8;
            __builtin_amdgcn_global_load_lds(
                (const __attribute__((address_space(1))) void*)ga,
                (__attribute__((address_space(3))) void*)la, 16, 0, 0);
            __builtin_amdgcn_global_load_lds(
                (const __attribute__((address_space(1))) void*)gb,
                (__attribute__((address_space(3))) void*)lb, 16, 0, 0);
        }
        __syncthreads();
#pragma unroll
        for (int ks = 0; ks < 2; ++ks) {
            bf16x8 af[4], bf[4];
#pragma unroll
            for (int i = 0; i < 4; ++i) {
                int rowa = wr * 64 + i * 16 + lr;
                af[i] = *(const bf16x8*)&As[rowa * 64 + (((ks << 2) | kg) ^ (rowa & 7)) * 8];
                int rowb = wc * 64 + i * 16 + lr;
                bf[i] = *(const bf16x8*)&Bs[rowb * 64 + (((ks << 2) | kg) ^ (rowb & 7)) * 8];
            }
#pragma unroll
            for (int i = 0; i < 4; ++i)
#pragma unroll
                for (int j = 0; j < 4; ++j)
                    acc[i][j] = __builtin_amdgcn_mfma_f32_16x16x32_bf16(
                        af[i], bf[j], acc[i][j], 0, 0, 0);
        }
        __syncthreads();
    }

    // ---- fused attention logits: head = n0/64 + wc ----
    int head = (n0 >> 6) + wc;
    float asv[4], adv[4];
#pragma unroll
    for (int j = 0; j < 4; ++j) {
        int cc = n0 + wc * 64 + j * 16 + lr;
        asv[j] = a_s[cc];
        adv[j] = a_d[cc];
    }
#pragma unroll
    for (int i = 0; i < 4; ++i) {
#pragma unroll
        for (int reg = 0; reg < 4; ++reg) {
            float ps = 0.f, pd = 0.f;
#pragma unroll
            for (int j = 0; j < 4; ++j) {
                ps += acc[i][j][reg] * asv[j];
                pd += acc[i][j][reg] * adv[j];
            }
#pragma unroll
            for (int d = 1; d < 16; d <<= 1) {
                ps += __shfl_xor(ps, d);
                pd += __shfl_xor(pd, d);
            }
            if (lr == 0) {
                int r = m0 + wr * 64 + i * 16 + kg * 4 + reg;
                alS[(size_t)r * HH + head] = ps;
                alD[(size_t)r * HH + head] = pd;
            }
        }
    }

#pragma unroll
    for (int i = 0; i < 4; ++i) {
        int rb = m0 + wr * 64 + i * 16 + kg * 4;
#pragma unroll
        for (int j = 0; j < 4; ++j) {
            int cc = n0 + wc * 64 + j * 16 + lr;
#pragma unroll
            for (int reg = 0; reg < 4; ++reg)
                Cb[(size_t)(rb + reg) * N + cc] = f2bf(acc[i][j][reg]);
        }
    }
}

// ---------------- generic fp32 tiled GEMM (layer 3 only) ----------------
__global__ __launch_bounds__(256) void gemm_tiled(
    const float* __restrict__ A, const float* __restrict__ B, float* __restrict__ C,
    int M, int N, int K) {
    __shared__ float As[16][68];
    __shared__ float Bs[16][64];
    int tid = threadIdx.x;
    int tx = tid & 15, ty = tid >> 4;
    int m0 = blockIdx.x * 64, n0 = blockIdx.y * 64;
    float acc[4][4] = {};
    int arow = tid >> 2;
    int akq = (tid & 3) * 4;
    int bk  = tid >> 4;
    int bnq = (tid & 15) * 4;
    for (int k0 = 0; k0 < K; k0 += 16) {
        {
            int grow = m0 + arow;
            if (grow < M) {
                const float* p = &A[(size_t)grow * K + k0 + akq];
                float4 v = *(const float4*)p;
                As[akq + 0][arow] = v.x; As[akq + 1][arow] = v.y;
                As[akq + 2][arow] = v.z; As[akq + 3][arow] = v.w;
            } else {
                As[akq + 0][arow] = 0.f; As[akq + 1][arow] = 0.f;
                As[akq + 2][arow] = 0.f; As[akq + 3][arow] = 0.f;
            }
        }
        {
            int gn = n0 + bnq;
            const float* p = &B[(size_t)(k0 + bk) * N + gn];
            if (gn + 3 < N) {
                *(float4*)&Bs[bk][bnq] = *(const float4*)p;
            } else {
#pragma unroll
                for (int j = 0; j < 4; ++j)
                    Bs[bk][bnq + j] = (gn + j < N) ? p[j] : 0.f;
            }
        }
        __syncthreads();
#pragma unroll
        for (int k = 0; k < 16; ++k) {
            float4 a4 = *(const float4*)&As[k][ty * 4];
            float4 b4 = *(const float4*)&Bs[k][tx * 4];
            float av[4] = {a4.x, a4.y, a4.z, a4.w};
            float bv[4] = {b4.x, b4.y, b4.z, b4.w};
#pragma unroll
            for (int i = 0; i < 4; ++i)
#pragma unroll
                for (int j = 0; j < 4; ++j)
                    acc[i][j] += av[i] * bv[j];
        }
        __syncthreads();
    }
#pragma unroll
    for (int i = 0; i < 4; ++i) {
        int r = m0 + ty * 4 + i;
        if (r >= M) continue;
#pragma unroll
        for (int j = 0; j < 4; ++j) {
            int cidx = n0 + tx * 4 + j;
            if (cidx < N) C[(size_t)r * N + cidx] = acc[i][j];
        }
    }
}

// ---------------- layer-3 attention logits (F=40, C=5) ----------------
__global__ void al40_kernel(const float* __restrict__ h3, const float* __restrict__ as3,
                            const float* __restrict__ ad3, float* __restrict__ al_s,
                            float* __restrict__ al_d) {
    int n = blockIdx.x * blockDim.x + threadIdx.x;
    if (n >= NN) return;
#pragma unroll
    for (int hh = 0; hh < HH; ++hh) {
        float s = 0.f, d = 0.f;
#pragma unroll
        for (int c = 0; c < C3; ++c) {
            float v = h3[(size_t)n * F3 + hh * C3 + c];
            s += v * as3[hh * C3 + c];
            d += v * ad3[hh * C3 + c];
        }
        al_s[n * HH + hh] = s;
        al_d[n * HH + hh] = d;
    }
}

// ---------------- layer-3 attention + head-mean + bias + log_softmax ----------------
__global__ __launch_bounds__(64) void attn3_kernel(
    const float* __restrict__ h3, const float* __restrict__ al_s,
    const float* __restrict__ al_d, const int* __restrict__ offs,
    const int* __restrict__ srcs, const float* __restrict__ b3,
    float* __restrict__ out) {
    int n = blockIdx.x;
    int t = threadIdx.x;
    int beg = offs[n], end = offs[n + 1];
    __shared__ float m_s[HH], idn_s[HH], ald_sh[HH];
    __shared__ float accs[HH][C3];
    __shared__ float vv[C3];
    if (t < HH) ald_sh[t] = al_d[n * HH + t];
    __syncthreads();
    if (t < HH) {
        float ald = ald_sh[t];
        float m = -1e30f;
        for (int e = beg; e < end; ++e) {
            int s = srcs[e];
            float sc = al_s[s * HH + t] + ald;
            sc = sc > 0.f ? sc : 0.2f * sc;
            m = fmaxf(m, sc);
        }
        float den = 0.f;
        for (int e = beg; e < end; ++e) {
            int s = srcs[e];
            float sc = al_s[s * HH + t] + ald;
            sc = sc > 0.f ? sc : 0.2f * sc;
            den += __expf(sc - m);
        }
        m_s[t] = m;
        idn_s[t] = 1.f / (den + 1e-16f);
    }
    __syncthreads();
    if (t < F3) {
        int hh = t / C3;
        int c = t - hh * C3;
        float m = m_s[hh], idn = idn_s[hh], ald = ald_sh[hh];
        float acc = 0.f;
        for (int e = beg; e < end; ++e) {
            int s = srcs[e];
            float sc = al_s[s * HH + hh] + ald;
            sc = sc > 0.f ? sc : 0.2f * sc;
            float a = __expf(sc - m) * idn;
            acc += a * h3[(size_t)s * F3 + t];
        }
        accs[hh][c] = acc;
    }
    __syncthreads();
    if (t < C3) {
        float s = 0.f;
#pragma unroll
        for (int hh = 0; hh < HH; ++hh) s += accs[hh][t];
        vv[t] = s * 0.125f + b3[t];
    }
    __syncthreads();
    if (t < C3) {
        float mx = vv[0];
#pragma unroll
        for (int c = 1; c < C3; ++c) mx = fmaxf(mx, vv[c]);
        float se = 0.f;
#pragma unroll
        for (int c = 0; c < C3; ++c) se += __expf(vv[c] - mx);
        out[(size_t)n * C3 + t] = vv[t] - mx - logf(se);
    }
}

// ---------------- host launcher ----------------
extern "C" void kernel_launch(void* const* d_in, const int* in_sizes, int n_in,
                              void* d_out, int out_size, void* d_ws, size_t ws_size,
                              hipStream_t stream) {
    const float* x   = (const float*)d_in[0];
    const int*   ei  = (const int*)d_in[1];
    const float* W1  = (const float*)d_in[2];
    const float* as1 = (const float*)d_in[3];
    const float* ad1 = (const float*)d_in[4];
    const float* b1  = (const float*)d_in[5];
    const float* W2  = (const float*)d_in[6];
    const float* as2 = (const float*)d_in[7];
    const float* ad2 = (const float*)d_in[8];
    const float* b2  = (const float*)d_in[9];
    const float* W3  = (const float*)d_in[10];
    const float* as3 = (const float*)d_in[11];
    const float* ad3 = (const float*)d_in[12];
    const float* b3  = (const float*)d_in[13];
    float* out = (float*)d_out;

    // ---- workspace layout (lifetime-aliased, ~167 MB) ----
    auto au = [](size_t v) { return (v + 255) & ~(size_t)255; };
    char* p = (char*)d_ws;
    size_t szHb = au((size_t)MP * FF * 2);           // 51.25 MB
    char* r1 = p;                                    // R1
    unsigned short* Hb1 = (unsigned short*)r1;
    unsigned short* Hb2 = (unsigned short*)r1;
    p += szHb;
    char* r2 = p;                                    // R2
    unsigned short* A2  = (unsigned short*)r2;
    unsigned short* W2T = (unsigned short*)(r2 + szHb);
    float* Bbuf = (float*)r2;
    {
        size_t a = szHb + au((size_t)FF * FF * 2);
        size_t b = au((size_t)NN * FF * 4);
        p = r2 + (a > b ? a : b);
    }
    float* alS  = (float*)p;  p += au((size_t)MP * HH * 4);
    float* alD  = (float*)p;  p += au((size_t)MP * HH * 4);
    float* h3   = (float*)p;  p += au((size_t)NN * F3 * 4);
    int* offs   = (int*)p;    p += au((size_t)(NN + 1) * 4);
    int* cnt    = (int*)p;    p += au((size_t)NN * 4);
    int* srcs   = (int*)p;    p += au((size_t)ETOT * 4);
    int* bsum   = (int*)p;    p += au(64 * 4);

    // ---- CSR build (dst-sorted) + prep ----
    zero_int_kernel<<<(NN + 255) / 256, 256, 0, stream>>>(cnt, NN);
    count_kernel<<<(ETOT + 255) / 256, 256, 0, stream>>>(ei, cnt);
    scan_blocks<<<NBLK, 1024, 0, stream>>>(cnt, offs, bsum);
    scan_sums<<<1, 64, 0, stream>>>(bsum);
    scan_add<<<NBLK, 1024, 0, stream>>>(offs, bsum);
    zero_int_kernel<<<(NN + 255) / 256, 256, 0, stream>>>(cnt, NN);
    scatter_kernel<<<(ETOT + 255) / 256, 256, 0, stream>>>(ei, offs, cnt, srcs);
    zero_tail_kernel<<<((MP - NN) * FF + 255) / 256, 256, 0, stream>>>(A2);
    prep_w2t<<<(FF * FF + 255) / 256, 256, 0, stream>>>(W2, W2T);

    // ---- layer 1 ----
    gemm1_fused<<<(NN + 63) / 64, 256, 0, stream>>>(x, W1, as1, ad1, Hb1, alS, alD);
    attn_gather<<<(NN + 3) / 4, 256, 0, stream>>>(Hb1, alS, alD, offs, srcs, b1,
                                                  nullptr, A2, 1);

    // ---- layer 2: bf16 MFMA GEMM (+ fused logits) ----
    gemm_mfma<<<dim3(MP / 128, FF / 128), 256, 0, stream>>>(
        A2, W2T, as2, ad2, Hb2, alS, alD, FF, FF);
    attn_gather<<<(NN + 3) / 4, 256, 0, stream>>>(Hb2, alS, alD, offs, srcs, b2,
                                                  Bbuf, nullptr, 1);

    // ---- layer 3 ----
    gemm_tiled<<<dim3((NN + 63) / 64, 1), 256, 0, stream>>>(Bbuf, W3, h3, NN, F3, FF);
    al40_kernel<<<(NN + 255) / 256, 256, 0, stream>>>(h3, as3, ad3, alS, alD);
    attn3_kernel<<<NN, 64, 0, stream>>>(h3, alS, alD, offs, srcs, b3, out);
}

// Round 8
// 373.395 us; speedup vs baseline: 4.3650x; 1.2438x over previous
//
#include <hip/hip_runtime.h>
#include <hip/hip_bf16.h>

#define NN    50000   // nodes
#define MP    50048   // padded to 128*391 for MFMA GEMM
#define E0C   400000  // raw edges
#define ETOT  450000  // + self loops
#define HH    8
#define FF    512     // H*C layers 1-2
#define F3    40      // H*C3 layer 3
#define C3    5
#define MAXE  128     // LDS alpha-cache capacity (deg ~ Poisson(8)+1)
#define NBLK  ((NN + 1023) / 1024)   // 49 scan blocks

typedef __attribute__((ext_vector_type(8))) short bf16x8;
typedef __attribute__((ext_vector_type(8))) short s16x8;
typedef __attribute__((ext_vector_type(4))) float f32x4;

__device__ inline unsigned short f2bf(float f) {
    union { float f; unsigned int u; } v; v.f = f;
    unsigned int r = v.u + 0x7FFF + ((v.u >> 16) & 1);
    return (unsigned short)(r >> 16);
}
__device__ inline float bf2f(unsigned short u) {
    union { unsigned int i; float f; } v; v.i = ((unsigned int)u) << 16;
    return v.f;
}

// ---------------- utility ----------------
__global__ void zero_int_kernel(int* p, int n) {
    int i = blockIdx.x * blockDim.x + threadIdx.x;
    if (i < n) p[i] = 0;
}

__global__ void zero_tail_kernel(unsigned short* A2) {
    int i = blockIdx.x * blockDim.x + threadIdx.x;
    int total = (MP - NN) * FF;
    if (i < total) A2[(size_t)NN * FF + i] = 0;
}

// ---------------- CSR build ----------------
__global__ void count_kernel(const int* __restrict__ ei, int* __restrict__ cnt) {
    int e = blockIdx.x * blockDim.x + threadIdx.x;
    if (e >= ETOT) return;
    int dst = (e < E0C) ? ei[E0C + e] : (e - E0C);
    atomicAdd(&cnt[dst], 1);
}

__global__ __launch_bounds__(1024) void scan_blocks(const int* __restrict__ cnt,
                                                    int* __restrict__ offs,
                                                    int* __restrict__ bsum) {
    __shared__ int s[1024];
    int tid = threadIdx.x;
    int i = blockIdx.x * 1024 + tid;
    s[tid] = (i < NN) ? cnt[i] : 0;
    __syncthreads();
    for (int d = 1; d < 1024; d <<= 1) {
        int add = (tid >= d) ? s[tid - d] : 0;
        __syncthreads();
        s[tid] += add;
        __syncthreads();
    }
    if (i < NN) offs[i + 1] = s[tid];
    if (tid == 1023) bsum[blockIdx.x] = s[1023];
}

__global__ __launch_bounds__(64) void scan_sums(int* __restrict__ bsum) {
    int lane = threadIdx.x;
    int v = (lane < NBLK) ? bsum[lane] : 0;
    int orig = v;
#pragma unroll
    for (int d = 1; d < 64; d <<= 1) {
        int o = __shfl_up(v, d);
        if (lane >= d) v += o;
    }
    if (lane < NBLK) bsum[lane] = v - orig;   // exclusive prefix
}

__global__ __launch_bounds__(1024) void scan_add(int* __restrict__ offs,
                                                 const int* __restrict__ bsum) {
    int i = blockIdx.x * 1024 + threadIdx.x;
    if (i < NN) offs[i + 1] += bsum[blockIdx.x];
    if (i == 0) offs[0] = 0;
}

__global__ void scatter_kernel(const int* __restrict__ ei, const int* __restrict__ offs,
                               int* __restrict__ cur, int* __restrict__ srcs) {
    int e = blockIdx.x * blockDim.x + threadIdx.x;
    if (e >= ETOT) return;
    int src, dst;
    if (e < E0C) { src = ei[e]; dst = ei[E0C + e]; }
    else         { src = dst = e - E0C; }
    int pos = offs[dst] + atomicAdd(&cur[dst], 1);
    srcs[pos] = src;
}

// ---------------- layer 1 GEMM (K=12) fused with logits, 64 nodes/block ------
__global__ __launch_bounds__(256) void gemm1_fused(
    const float* __restrict__ x, const float* __restrict__ W1,
    const float* __restrict__ as1, const float* __restrict__ ad1,
    unsigned short* __restrict__ hb, float* __restrict__ al_s,
    float* __restrict__ al_d) {
    __shared__ float xs[64 * 12];
    int t = threadIdx.x;
    int n0 = blockIdx.x * 64;
    int nvalid = NN - n0; if (nvalid > 64) nvalid = 64;

    for (int j = t; j < nvalid * 12; j += 256) xs[j] = x[(size_t)n0 * 12 + j];
    __syncthreads();

    int f = t * 2;
    float w0[12], w1[12];
#pragma unroll
    for (int k = 0; k < 12; ++k) {
        float2 wv = *(const float2*)&W1[k * FF + f];
        w0[k] = wv.x; w1[k] = wv.y;
    }
    float2 asv = *(const float2*)&as1[f];
    float2 adv = *(const float2*)&ad1[f];
    int head = t >> 5;

    for (int ni = 0; ni < nvalid; ++ni) {
        const float* xp = &xs[ni * 12];
        float4 xa = *(const float4*)xp;
        float4 xb = *(const float4*)(xp + 4);
        float4 xc = *(const float4*)(xp + 8);
        float xv[12] = {xa.x, xa.y, xa.z, xa.w, xb.x, xb.y, xb.z, xb.w,
                        xc.x, xc.y, xc.z, xc.w};
        float h0 = 0.f, h1 = 0.f;
#pragma unroll
        for (int k = 0; k < 12; ++k) { h0 += xv[k] * w0[k]; h1 += xv[k] * w1[k]; }
        unsigned int u = ((unsigned int)f2bf(h1) << 16) | f2bf(h0);
        *(unsigned int*)&hb[(size_t)(n0 + ni) * FF + f] = u;
        float ps = h0 * asv.x + h1 * asv.y;
        float pd = h0 * adv.x + h1 * adv.y;
#pragma unroll
        for (int d = 1; d < 32; d <<= 1) {
            ps += __shfl_xor(ps, d);
            pd += __shfl_xor(pd, d);
        }
        if ((t & 31) == 0) {
            al_s[(size_t)(n0 + ni) * HH + head] = ps;
            al_d[(size_t)(n0 + ni) * HH + head] = pd;
        }
    }
}

// ---------------- attention aggregate: ONE WAVE PER NODE, bf16 gather ----------
__global__ __launch_bounds__(256) void attn_gather(
    const unsigned short* __restrict__ Hb,   // [*,FF] bf16
    const float* __restrict__ alS, const float* __restrict__ alD,
    const int* __restrict__ offs, const int* __restrict__ srcs,
    const float* __restrict__ bias,
    float* __restrict__ out_f32, unsigned short* __restrict__ out_b16, int relu) {
    __shared__ float alpha_sh[4][MAXE][HH];
    __shared__ int   srcs_sh[4][MAXE];
    int w = threadIdx.x >> 6, lane = threadIdx.x & 63;
    int n = blockIdx.x * 4 + w;
    if (n >= NN) return;
    int h = lane >> 3, es = lane & 7;
    int beg = offs[n], end = offs[n + 1], deg = end - beg;

    float ald = alD[n * HH + h];
    float m = -1e30f;
    for (int e = es; e < deg; e += 8) {
        int s = srcs[beg + e];
        float sc = alS[s * HH + h] + ald;
        sc = sc > 0.f ? sc : 0.2f * sc;
        m = fmaxf(m, sc);
    }
    m = fmaxf(m, __shfl_xor(m, 1));
    m = fmaxf(m, __shfl_xor(m, 2));
    m = fmaxf(m, __shfl_xor(m, 4));
    float den = 0.f;
    for (int e = es; e < deg; e += 8) {
        int s = srcs[beg + e];
        if (h == 0 && e < MAXE) srcs_sh[w][e] = s;
        float sc = alS[s * HH + h] + ald;
        sc = sc > 0.f ? sc : 0.2f * sc;
        float ex = __expf(sc - m);
        den += ex;
        if (e < MAXE) alpha_sh[w][e][h] = ex;
    }
    den += __shfl_xor(den, 1);
    den += __shfl_xor(den, 2);
    den += __shfl_xor(den, 4);
    float idn = 1.f / (den + 1e-16f);
    int cap = deg < MAXE ? deg : MAXE;
    for (int e = es; e < cap; e += 8) alpha_sh[w][e][h] *= idn;

    int f0 = lane * 8;
    float acc[8] = {};
    if (deg <= MAXE) {
        for (int e = 0; e < deg; ++e) {
            int s = srcs_sh[w][e];
            float a = alpha_sh[w][e][h];
            bf16x8 v = *(const bf16x8*)&Hb[(size_t)s * FF + f0];
#pragma unroll
            for (int k = 0; k < 8; ++k)
                acc[k] += a * bf2f((unsigned short)v[k]);
        }
    } else {
        for (int e = 0; e < deg; ++e) {
            int s = srcs[beg + e];
            float sc = alS[s * HH + h] + ald;
            sc = sc > 0.f ? sc : 0.2f * sc;
            float a = __expf(sc - m) * idn;
            bf16x8 v = *(const bf16x8*)&Hb[(size_t)s * FF + f0];
#pragma unroll
            for (int k = 0; k < 8; ++k)
                acc[k] += a * bf2f((unsigned short)v[k]);
        }
    }
    float4 b0 = *(const float4*)&bias[f0];
    float4 b1 = *(const float4*)&bias[f0 + 4];
    float bv[8] = {b0.x, b0.y, b0.z, b0.w, b1.x, b1.y, b1.z, b1.w};
    float vv[8];
#pragma unroll
    for (int k = 0; k < 8; ++k) {
        float t = acc[k] + bv[k];
        vv[k] = relu ? fmaxf(t, 0.f) : t;
    }
    if (out_f32) {
        float4 o0 = {vv[0], vv[1], vv[2], vv[3]};
        float4 o1 = {vv[4], vv[5], vv[6], vv[7]};
        *(float4*)&out_f32[(size_t)n * FF + f0] = o0;
        *(float4*)&out_f32[(size_t)n * FF + f0 + 4] = o1;
    }
    if (out_b16) {
        s16x8 ov;
#pragma unroll
        for (int k = 0; k < 8; ++k) ov[k] = (short)f2bf(vv[k]);
        *(s16x8*)&out_b16[(size_t)n * FF + f0] = ov;
    }
}

// ---------------- W2 -> W2^T bf16 (N x K) ----------------
__global__ void prep_w2t(const float* __restrict__ W2, unsigned short* __restrict__ W2T) {
    int i = blockIdx.x * blockDim.x + threadIdx.x;
    if (i >= FF * FF) return;
    int n = i >> 9, k = i & 511;
    W2T[i] = f2bf(W2[k * FF + n]);
}

// ---------------- W3 -> W3^T bf16, padded to 48 rows ----------------
__global__ void prep_w3t(const float* __restrict__ W3, unsigned short* __restrict__ W3T) {
    int i = blockIdx.x * blockDim.x + threadIdx.x;
    if (i >= 48 * 512) return;
    int n = i >> 9, k = i & 511;
    W3T[i] = (n < F3) ? f2bf(W3[k * F3 + n]) : 0;
}

// ---------------- bf16 MFMA GEMM + fused logits, bf16 output (2-phase dbuf) ---
__global__ __launch_bounds__(256) void gemm_mfma(
    const unsigned short* __restrict__ A,   // [MP][K] bf16
    const unsigned short* __restrict__ BT,  // [N][K]  bf16
    const float* __restrict__ a_s, const float* __restrict__ a_d,  // [N]
    unsigned short* __restrict__ Cb,        // [MP][N] bf16
    float* __restrict__ alS, float* __restrict__ alD,              // [MP][HH]
    int N, int K) {
    __shared__ unsigned short As[2][128 * 64];
    __shared__ unsigned short Bs[2][128 * 64];
    int t = threadIdx.x;
    int wave = t >> 6, lane = t & 63;
    int wr = wave >> 1, wc = wave & 1;
    int m0 = blockIdx.x * 128, n0 = blockIdx.y * 128;

    f32x4 acc[4][4] = {};
    int kg = lane >> 4;
    int lr = lane & 15;

    auto STAGE = [&](int buf, int k0) {
#pragma unroll
        for (int q = 0; q < 4; ++q) {
            int c   = q * 256 + t;
            int row = c >> 3, kc = c & 7;
            int kcs = kc ^ (row & 7);
            const unsigned short* ga = A + (size_t)(m0 + row) * K + k0 + kcs * 8;
            const unsigned short* gb = BT + (size_t)(n0 + row) * K + k0 + kcs * 8;
            unsigned short* la = &As[buf][(size_t)(q * 256 + wave * 64) * 8];
            unsigned short* lb = &Bs[buf][(size_t)(q * 256 + wave * 64) * 8];
            __builtin_amdgcn_global_load_lds(
                (const __attribute__((address_space(1))) void*)ga,
                (__attribute__((address_space(3))) void*)la, 16, 0, 0);
            __builtin_amdgcn_global_load_lds(
                (const __attribute__((address_space(1))) void*)gb,
                (__attribute__((address_space(3))) void*)lb, 16, 0, 0);
        }
    };

    const int NT = K / 64;
    STAGE(0, 0);
    __syncthreads();
    int cur = 0;
    for (int kt = 0; kt < NT; ++kt) {
        if (kt + 1 < NT) STAGE(cur ^ 1, (kt + 1) * 64);
        const unsigned short* Ac = As[cur];
        const unsigned short* Bc = Bs[cur];
#pragma unroll
        for (int ks = 0; ks < 2; ++ks) {
            bf16x8 af[4], bf[4];
#pragma unroll
            for (int i = 0; i < 4; ++i) {
                int rowa = wr * 64 + i * 16 + lr;
                af[i] = *(const bf16x8*)&Ac[rowa * 64 + (((ks << 2) | kg) ^ (rowa & 7)) * 8];
                int rowb = wc * 64 + i * 16 + lr;
                bf[i] = *(const bf16x8*)&Bc[rowb * 64 + (((ks << 2) | kg) ^ (rowb & 7)) * 8];
            }
#pragma unroll
            for (int i = 0; i < 4; ++i)
#pragma unroll
                for (int j = 0; j < 4; ++j)
                    acc[i][j] = __builtin_amdgcn_mfma_f32_16x16x32_bf16(
                        af[i], bf[j], acc[i][j], 0, 0, 0);
        }
        __syncthreads();   // drains prefetch vmcnt + compute lgkm; buffers swap
        cur ^= 1;
    }

    // ---- fused attention logits: head = n0/64 + wc ----
    int head = (n0 >> 6) + wc;
    float asv[4], adv[4];
#pragma unroll
    for (int j = 0; j < 4; ++j) {
        int cc = n0 + wc * 64 + j * 16 + lr;
        asv[j] = a_s[cc];
        adv[j] = a_d[cc];
    }
#pragma unroll
    for (int i = 0; i < 4; ++i) {
#pragma unroll
        for (int reg = 0; reg < 4; ++reg) {
            float ps = 0.f, pd = 0.f;
#pragma unroll
            for (int j = 0; j < 4; ++j) {
                ps += acc[i][j][reg] * asv[j];
                pd += acc[i][j][reg] * adv[j];
            }
#pragma unroll
            for (int d = 1; d < 16; d <<= 1) {
                ps += __shfl_xor(ps, d);
                pd += __shfl_xor(pd, d);
            }
            if (lr == 0) {
                int r = m0 + wr * 64 + i * 16 + kg * 4 + reg;
                alS[(size_t)r * HH + head] = ps;
                alD[(size_t)r * HH + head] = pd;
            }
        }
    }

#pragma unroll
    for (int i = 0; i < 4; ++i) {
        int rb = m0 + wr * 64 + i * 16 + kg * 4;
#pragma unroll
        for (int j = 0; j < 4; ++j) {
            int cc = n0 + wc * 64 + j * 16 + lr;
#pragma unroll
            for (int reg = 0; reg < 4; ++reg)
                Cb[(size_t)(rb + reg) * N + cc] = f2bf(acc[i][j][reg]);
        }
    }
}

// ---------------- layer-3 MFMA GEMM: h3[MP,40] = A[MP,512] @ W3T[48,512]^T ----
// 128-row tile, N=48 (3 frags, cols>=40 dropped), 4 waves each 32 rows.
__global__ __launch_bounds__(256) void gemm3_mfma(
    const unsigned short* __restrict__ A,    // [MP][512] bf16
    const unsigned short* __restrict__ BT,   // [48][512] bf16
    float* __restrict__ C) {                 // [NN][40] f32
    __shared__ unsigned short As[128 * 64];
    __shared__ unsigned short Bs[48 * 64];
    int t = threadIdx.x;
    int wave = t >> 6, lane = t & 63;
    int m0 = blockIdx.x * 128;
    int kg = lane >> 4, lr = lane & 15;

    f32x4 acc[2][3] = {};

    for (int k0 = 0; k0 < 512; k0 += 64) {
#pragma unroll
        for (int q = 0; q < 4; ++q) {
            int c   = q * 256 + t;
            int row = c >> 3, kc = c & 7;
            int kcs = kc ^ (row & 7);
            const unsigned short* ga = A + (size_t)(m0 + row) * 512 + k0 + kcs * 8;
            unsigned short* la = &As[(size_t)(q * 256 + wave * 64) * 8];
            __builtin_amdgcn_global_load_lds(
                (const __attribute__((address_space(1))) void*)ga,
                (__attribute__((address_space(3))) void*)la, 16, 0, 0);
        }
        {
            int c   = t;           // chunks 0..255
            int row = c >> 3, kc = c & 7;
            int kcs = kc ^ (row & 7);
            const unsigned short* gb = BT + (size_t)row * 512 + k0 + kcs * 8;
            unsigned short* lb = &Bs[(size_t)(wave * 64) * 8];
            __builtin_amdgcn_global_load_lds(
                (const __attribute__((address_space(1))) void*)gb,
                (__attribute__((address_space(3))) void*)lb, 16, 0, 0);
        }
        if (t < 128) {             // chunks 256..383
            int c   = 256 + t;
            int row = c >> 3, kc = c & 7;
            int kcs = kc ^ (row & 7);
            const unsigned short* gb = BT + (size_t)row * 512 + k0 + kcs * 8;
            unsigned short* lb = &Bs[(size_t)(256 + wave * 64) * 8];
            __builtin_amdgcn_global_load_lds(
                (const __attribute__((address_space(1))) void*)gb,
                (__attribute__((address_space(3))) void*)lb, 16, 0, 0);
        }
        __syncthreads();
#pragma unroll
        for (int ks = 0; ks < 2; ++ks) {
            bf16x8 af[2], bf[3];
#pragma unroll
            for (int i = 0; i < 2; ++i) {
                int rowa = wave * 32 + i * 16 + lr;
                af[i] = *(const bf16x8*)&As[rowa * 64 + (((ks << 2) | kg) ^ (rowa & 7)) * 8];
            }
#pragma unroll
            for (int j = 0; j < 3; ++j) {
                int rowb = j * 16 + lr;
                bf[j] = *(const bf16x8*)&Bs[rowb * 64 + (((ks << 2) | kg) ^ (rowb & 7)) * 8];
            }
#pragma unroll
            for (int i = 0; i < 2; ++i)
#pragma unroll
                for (int j = 0; j < 3; ++j)
                    acc[i][j] = __builtin_amdgcn_mfma_f32_16x16x32_bf16(
                        af[i], bf[j], acc[i][j], 0, 0, 0);
        }
        __syncthreads();
    }

#pragma unroll
    for (int i = 0; i < 2; ++i) {
        int rb = m0 + wave * 32 + i * 16 + kg * 4;
#pragma unroll
        for (int j = 0; j < 3; ++j) {
            int cc = j * 16 + lr;
            if (cc >= F3) continue;
#pragma unroll
            for (int reg = 0; reg < 4; ++reg) {
                int r = rb + reg;
                if (r < NN) C[(size_t)r * F3 + cc] = acc[i][j][reg];
            }
        }
    }
}

// ---------------- layer-3 attention logits (F=40, C=5) ----------------
__global__ void al40_kernel(const float* __restrict__ h3, const float* __restrict__ as3,
                            const float* __restrict__ ad3, float* __restrict__ al_s,
                            float* __restrict__ al_d) {
    int n = blockIdx.x * blockDim.x + threadIdx.x;
    if (n >= NN) return;
#pragma unroll
    for (int hh = 0; hh < HH; ++hh) {
        float s = 0.f, d = 0.f;
#pragma unroll
        for (int c = 0; c < C3; ++c) {
            float v = h3[(size_t)n * F3 + hh * C3 + c];
            s += v * as3[hh * C3 + c];
            d += v * ad3[hh * C3 + c];
        }
        al_s[n * HH + hh] = s;
        al_d[n * HH + hh] = d;
    }
}

// ---------------- layer-3 attention, wave-parallel (4 nodes/block) ------------
// + head-mean + bias + log_softmax. NN % 4 == 0 so every wave has a node.
__global__ __launch_bounds__(256) void attn3_kernel(
    const float* __restrict__ h3, const float* __restrict__ al_s,
    const float* __restrict__ al_d, const int* __restrict__ offs,
    const int* __restrict__ srcs, const float* __restrict__ b3,
    float* __restrict__ out) {
    __shared__ float alpha_sh[4][MAXE][HH];
    __shared__ int   srcs_sh[4][MAXE];
    __shared__ float idn_sh[4][HH], m_sh[4][HH], ald_sh2[4][HH];
    __shared__ float accs[4][F3];
    __shared__ float vv[4][C3];
    int w = threadIdx.x >> 6, lane = threadIdx.x & 63;
    int n = blockIdx.x * 4 + w;
    int h = lane >> 3, es = lane & 7;
    int beg = offs[n], end = offs[n + 1], deg = end - beg;

    float ald = al_d[n * HH + h];
    float m = -1e30f;
    for (int e = es; e < deg; e += 8) {
        int s = srcs[beg + e];
        float sc = al_s[s * HH + h] + ald;
        sc = sc > 0.f ? sc : 0.2f * sc;
        m = fmaxf(m, sc);
    }
    m = fmaxf(m, __shfl_xor(m, 1));
    m = fmaxf(m, __shfl_xor(m, 2));
    m = fmaxf(m, __shfl_xor(m, 4));
    float den = 0.f;
    for (int e = es; e < deg; e += 8) {
        int s = srcs[beg + e];
        if (h == 0 && e < MAXE) srcs_sh[w][e] = s;
        float sc = al_s[s * HH + h] + ald;
        sc = sc > 0.f ? sc : 0.2f * sc;
        float ex = __expf(sc - m);
        den += ex;
        if (e < MAXE) alpha_sh[w][e][h] = ex;
    }
    den += __shfl_xor(den, 1);
    den += __shfl_xor(den, 2);
    den += __shfl_xor(den, 4);
    float idn = 1.f / (den + 1e-16f);
    if (es == 0) { idn_sh[w][h] = idn; m_sh[w][h] = m; ald_sh2[w][h] = ald; }
    __syncthreads();

    if (lane < F3) {
        int hh = lane / C3;
        float acc = 0.f;
        if (deg <= MAXE) {
            for (int e = 0; e < deg; ++e) {
                int s = srcs_sh[w][e];
                acc += alpha_sh[w][e][hh] * h3[(size_t)s * F3 + lane];
            }
        } else {
            float mm = m_sh[w][hh], aald = ald_sh2[w][hh];
            for (int e = 0; e < deg; ++e) {
                int s = srcs[beg + e];
                float sc = al_s[s * HH + hh] + aald;
                sc = sc > 0.f ? sc : 0.2f * sc;
                acc += __expf(sc - mm) * h3[(size_t)s * F3 + lane];
            }
        }
        accs[w][lane] = acc * idn_sh[w][hh];
    }
    __syncthreads();
    if (lane < C3) {
        float s = 0.f;
#pragma unroll
        for (int hh = 0; hh < HH; ++hh) s += accs[w][hh * C3 + lane];
        vv[w][lane] = s * 0.125f + b3[lane];
    }
    __syncthreads();
    if (lane < C3) {
        float mx = vv[w][0];
#pragma unroll
        for (int c = 1; c < C3; ++c) mx = fmaxf(mx, vv[w][c]);
        float se = 0.f;
#pragma unroll
        for (int c = 0; c < C3; ++c) se += __expf(vv[w][c] - mx);
        out[(size_t)n * C3 + lane] = vv[w][lane] - mx - logf(se);
    }
}

// ---------------- host launcher ----------------
extern "C" void kernel_launch(void* const* d_in, const int* in_sizes, int n_in,
                              void* d_out, int out_size, void* d_ws, size_t ws_size,
                              hipStream_t stream) {
    const float* x   = (const float*)d_in[0];
    const int*   ei  = (const int*)d_in[1];
    const float* W1  = (const float*)d_in[2];
    const float* as1 = (const float*)d_in[3];
    const float* ad1 = (const float*)d_in[4];
    const float* b1  = (const float*)d_in[5];
    const float* W2  = (const float*)d_in[6];
    const float* as2 = (const float*)d_in[7];
    const float* ad2 = (const float*)d_in[8];
    const float* b2  = (const float*)d_in[9];
    const float* W3  = (const float*)d_in[10];
    const float* as3 = (const float*)d_in[11];
    const float* ad3 = (const float*)d_in[12];
    const float* b3  = (const float*)d_in[13];
    float* out = (float*)d_out;

    // ---- workspace layout (lifetime-aliased, ~118 MB) ----
    // R1: Hb1 (layer1 h bf16) -> Hb2 (layer2 h bf16)            [MP][FF] bf16
    // R2: A2 (attn1 out bf16, MP tail zeroed) + W2T  -> Bb16 (attn2 out bf16,
    //     same pointer as A2, tail zeros survive)   + W3T
    auto au = [](size_t v) { return (v + 255) & ~(size_t)255; };
    char* p = (char*)d_ws;
    size_t szHb = au((size_t)MP * FF * 2);           // 51.25 MB
    char* r1 = p;
    unsigned short* Hb1 = (unsigned short*)r1;
    unsigned short* Hb2 = (unsigned short*)r1;
    p += szHb;
    char* r2 = p;
    unsigned short* A2   = (unsigned short*)r2;
    unsigned short* Bb16 = (unsigned short*)r2;      // alias: attn2 out
    unsigned short* W2T  = (unsigned short*)(r2 + szHb);
    p = r2 + szHb + au((size_t)FF * FF * 2);
    unsigned short* W3T = (unsigned short*)p;  p += au((size_t)48 * 512 * 2);
    float* alS  = (float*)p;  p += au((size_t)MP * HH * 4);
    float* alD  = (float*)p;  p += au((size_t)MP * HH * 4);
    float* h3   = (float*)p;  p += au((size_t)NN * F3 * 4);
    int* offs   = (int*)p;    p += au((size_t)(NN + 1) * 4);
    int* cnt    = (int*)p;    p += au((size_t)NN * 4);
    int* srcs   = (int*)p;    p += au((size_t)ETOT * 4);
    int* bsum   = (int*)p;    p += au(64 * 4);

    // ---- CSR build (dst-sorted) + prep ----
    zero_int_kernel<<<(NN + 255) / 256, 256, 0, stream>>>(cnt, NN);
    count_kernel<<<(ETOT + 255) / 256, 256, 0, stream>>>(ei, cnt);
    scan_blocks<<<NBLK, 1024, 0, stream>>>(cnt, offs, bsum);
    scan_sums<<<1, 64, 0, stream>>>(bsum);
    scan_add<<<NBLK, 1024, 0, stream>>>(offs, bsum);
    zero_int_kernel<<<(NN + 255) / 256, 256, 0, stream>>>(cnt, NN);
    scatter_kernel<<<(ETOT + 255) / 256, 256, 0, stream>>>(ei, offs, cnt, srcs);
    zero_tail_kernel<<<((MP - NN) * FF + 255) / 256, 256, 0, stream>>>(A2);
    prep_w2t<<<(FF * FF + 255) / 256, 256, 0, stream>>>(W2, W2T);
    prep_w3t<<<(48 * 512 + 255) / 256, 256, 0, stream>>>(W3, W3T);

    // ---- layer 1 ----
    gemm1_fused<<<(NN + 63) / 64, 256, 0, stream>>>(x, W1, as1, ad1, Hb1, alS, alD);
    attn_gather<<<(NN + 3) / 4, 256, 0, stream>>>(Hb1, alS, alD, offs, srcs, b1,
                                                  nullptr, A2, 1);

    // ---- layer 2: bf16 MFMA GEMM (+ fused logits), double-buffered ----
    gemm_mfma<<<dim3(MP / 128, FF / 128), 256, 0, stream>>>(
        A2, W2T, as2, ad2, Hb2, alS, alD, FF, FF);
    attn_gather<<<(NN + 3) / 4, 256, 0, stream>>>(Hb2, alS, alD, offs, srcs, b2,
                                                  nullptr, Bb16, 1);

    // ---- layer 3 ----
    gemm3_mfma<<<MP / 128, 256, 0, stream>>>(Bb16, W3T, h3);
    al40_kernel<<<(NN + 255) / 256, 256, 0, stream>>>(h3, as3, ad3, alS, alD);
    attn3_kernel<<<NN / 4, 256, 0, stream>>>(h3, alS, alD, offs, srcs, b3, out);
}

// Round 9
// 360.512 us; speedup vs baseline: 4.5210x; 1.0357x over previous
//
#include <hip/hip_runtime.h>
#include <hip/hip_bf16.h>

#define NN    50000   // nodes
#define MP    50048   // padded to 128*391 for MFMA GEMM
#define E0C   400000  // raw edges
#define ETOT  450000  // + self loops
#define HH    8
#define FF    512     // H*C layers 1-2
#define F3    40      // H*C3 layer 3
#define C3    5
#define MAXE  128     // LDS alpha-cache capacity (deg ~ Poisson(8)+1)
#define NBLK  ((NN + 1023) / 1024)   // 49 scan blocks
#define MT2   (MP / 128)             // 391 m-tiles layer-2 gemm
#define GT2   (MT2 * 4)              // 1564 blocks

typedef __attribute__((ext_vector_type(8))) short bf16x8;
typedef __attribute__((ext_vector_type(8))) short s16x8;
typedef __attribute__((ext_vector_type(4))) float f32x4;

__device__ inline unsigned short f2bf(float f) {
    union { float f; unsigned int u; } v; v.f = f;
    unsigned int r = v.u + 0x7FFF + ((v.u >> 16) & 1);
    return (unsigned short)(r >> 16);
}
__device__ inline float bf2f(unsigned short u) {
    union { unsigned int i; float f; } v; v.i = ((unsigned int)u) << 16;
    return v.f;
}

// ---------------- CSR build ----------------
__global__ void count_kernel(const int* __restrict__ ei, int* __restrict__ cnt) {
    int e = blockIdx.x * blockDim.x + threadIdx.x;
    if (e >= ETOT) return;
    int dst = (e < E0C) ? ei[E0C + e] : (e - E0C);
    atomicAdd(&cnt[dst], 1);
}

__global__ __launch_bounds__(1024) void scan_blocks(const int* __restrict__ cnt,
                                                    int* __restrict__ offs,
                                                    int* __restrict__ bsum) {
    __shared__ int s[1024];
    int tid = threadIdx.x;
    int i = blockIdx.x * 1024 + tid;
    s[tid] = (i < NN) ? cnt[i] : 0;
    __syncthreads();
    for (int d = 1; d < 1024; d <<= 1) {
        int add = (tid >= d) ? s[tid - d] : 0;
        __syncthreads();
        s[tid] += add;
        __syncthreads();
    }
    if (i < NN) offs[i + 1] = s[tid];
    if (tid == 1023) bsum[blockIdx.x] = s[1023];
}

__global__ __launch_bounds__(64) void scan_sums(int* __restrict__ bsum) {
    int lane = threadIdx.x;
    int v = (lane < NBLK) ? bsum[lane] : 0;
    int orig = v;
#pragma unroll
    for (int d = 1; d < 64; d <<= 1) {
        int o = __shfl_up(v, d);
        if (lane >= d) v += o;
    }
    if (lane < NBLK) bsum[lane] = v - orig;   // exclusive prefix
}

__global__ __launch_bounds__(1024) void scan_add(int* __restrict__ offs,
                                                 const int* __restrict__ bsum) {
    int i = blockIdx.x * 1024 + threadIdx.x;
    if (i < NN) offs[i + 1] += bsum[blockIdx.x];
    if (i == 0) offs[0] = 0;
}

__global__ void scatter_kernel(const int* __restrict__ ei, const int* __restrict__ offs,
                               int* __restrict__ cur, int* __restrict__ srcs) {
    int e = blockIdx.x * blockDim.x + threadIdx.x;
    if (e >= ETOT) return;
    int src, dst;
    if (e < E0C) { src = ei[e]; dst = ei[E0C + e]; }
    else         { src = dst = e - E0C; }
    int pos = offs[dst] + atomicAdd(&cur[dst], 1);
    srcs[pos] = src;
}

// ---------------- layer 1 GEMM (K=12) fused with logits, 64 nodes/block ------
__global__ __launch_bounds__(256) void gemm1_fused(
    const float* __restrict__ x, const float* __restrict__ W1,
    const float* __restrict__ as1, const float* __restrict__ ad1,
    unsigned short* __restrict__ hb, float* __restrict__ al_s,
    float* __restrict__ al_d) {
    __shared__ float xs[64 * 12];
    int t = threadIdx.x;
    int n0 = blockIdx.x * 64;
    int nvalid = NN - n0; if (nvalid > 64) nvalid = 64;

    for (int j = t; j < nvalid * 12; j += 256) xs[j] = x[(size_t)n0 * 12 + j];
    __syncthreads();

    int f = t * 2;
    float w0[12], w1[12];
#pragma unroll
    for (int k = 0; k < 12; ++k) {
        float2 wv = *(const float2*)&W1[k * FF + f];
        w0[k] = wv.x; w1[k] = wv.y;
    }
    float2 asv = *(const float2*)&as1[f];
    float2 adv = *(const float2*)&ad1[f];
    int head = t >> 5;

    for (int ni = 0; ni < nvalid; ++ni) {
        const float* xp = &xs[ni * 12];
        float4 xa = *(const float4*)xp;
        float4 xb = *(const float4*)(xp + 4);
        float4 xc = *(const float4*)(xp + 8);
        float xv[12] = {xa.x, xa.y, xa.z, xa.w, xb.x, xb.y, xb.z, xb.w,
                        xc.x, xc.y, xc.z, xc.w};
        float h0 = 0.f, h1 = 0.f;
#pragma unroll
        for (int k = 0; k < 12; ++k) { h0 += xv[k] * w0[k]; h1 += xv[k] * w1[k]; }
        unsigned int u = ((unsigned int)f2bf(h1) << 16) | f2bf(h0);
        *(unsigned int*)&hb[(size_t)(n0 + ni) * FF + f] = u;
        float ps = h0 * asv.x + h1 * asv.y;
        float pd = h0 * adv.x + h1 * adv.y;
#pragma unroll
        for (int d = 1; d < 32; d <<= 1) {
            ps += __shfl_xor(ps, d);
            pd += __shfl_xor(pd, d);
        }
        if ((t & 31) == 0) {
            al_s[(size_t)(n0 + ni) * HH + head] = ps;
            al_d[(size_t)(n0 + ni) * HH + head] = pd;
        }
    }
}

// ---------------- attention aggregate: ONE WAVE PER NODE, bf16 gather ----------
__global__ __launch_bounds__(256) void attn_gather(
    const unsigned short* __restrict__ Hb,   // [*,FF] bf16
    const float* __restrict__ alS, const float* __restrict__ alD,
    const int* __restrict__ offs, const int* __restrict__ srcs,
    const float* __restrict__ bias,
    float* __restrict__ out_f32, unsigned short* __restrict__ out_b16, int relu) {
    __shared__ float alpha_sh[4][MAXE][HH];
    __shared__ int   srcs_sh[4][MAXE];
    int w = threadIdx.x >> 6, lane = threadIdx.x & 63;
    int n = blockIdx.x * 4 + w;
    if (n >= NN) return;
    int h = lane >> 3, es = lane & 7;
    int beg = offs[n], end = offs[n + 1], deg = end - beg;

    float ald = alD[n * HH + h];
    float m = -1e30f;
    for (int e = es; e < deg; e += 8) {
        int s = srcs[beg + e];
        float sc = alS[s * HH + h] + ald;
        sc = sc > 0.f ? sc : 0.2f * sc;
        m = fmaxf(m, sc);
    }
    m = fmaxf(m, __shfl_xor(m, 1));
    m = fmaxf(m, __shfl_xor(m, 2));
    m = fmaxf(m, __shfl_xor(m, 4));
    float den = 0.f;
    for (int e = es; e < deg; e += 8) {
        int s = srcs[beg + e];
        if (h == 0 && e < MAXE) srcs_sh[w][e] = s;
        float sc = alS[s * HH + h] + ald;
        sc = sc > 0.f ? sc : 0.2f * sc;
        float ex = __expf(sc - m);
        den += ex;
        if (e < MAXE) alpha_sh[w][e][h] = ex;
    }
    den += __shfl_xor(den, 1);
    den += __shfl_xor(den, 2);
    den += __shfl_xor(den, 4);
    float idn = 1.f / (den + 1e-16f);
    int cap = deg < MAXE ? deg : MAXE;
    for (int e = es; e < cap; e += 8) alpha_sh[w][e][h] *= idn;

    int f0 = lane * 8;
    float acc[8] = {};
    if (deg <= MAXE) {
        for (int e = 0; e < deg; ++e) {
            int s = srcs_sh[w][e];
            float a = alpha_sh[w][e][h];
            bf16x8 v = *(const bf16x8*)&Hb[(size_t)s * FF + f0];
#pragma unroll
            for (int k = 0; k < 8; ++k)
                acc[k] += a * bf2f((unsigned short)v[k]);
        }
    } else {
        for (int e = 0; e < deg; ++e) {
            int s = srcs[beg + e];
            float sc = alS[s * HH + h] + ald;
            sc = sc > 0.f ? sc : 0.2f * sc;
            float a = __expf(sc - m) * idn;
            bf16x8 v = *(const bf16x8*)&Hb[(size_t)s * FF + f0];
#pragma unroll
            for (int k = 0; k < 8; ++k)
                acc[k] += a * bf2f((unsigned short)v[k]);
        }
    }
    float4 b0 = *(const float4*)&bias[f0];
    float4 b1 = *(const float4*)&bias[f0 + 4];
    float bv[8] = {b0.x, b0.y, b0.z, b0.w, b1.x, b1.y, b1.z, b1.w};
    float vv[8];
#pragma unroll
    for (int k = 0; k < 8; ++k) {
        float t = acc[k] + bv[k];
        vv[k] = relu ? fmaxf(t, 0.f) : t;
    }
    if (out_f32) {
        float4 o0 = {vv[0], vv[1], vv[2], vv[3]};
        float4 o1 = {vv[4], vv[5], vv[6], vv[7]};
        *(float4*)&out_f32[(size_t)n * FF + f0] = o0;
        *(float4*)&out_f32[(size_t)n * FF + f0 + 4] = o1;
    }
    if (out_b16) {
        s16x8 ov;
#pragma unroll
        for (int k = 0; k < 8; ++k) ov[k] = (short)f2bf(vv[k]);
        *(s16x8*)&out_b16[(size_t)n * FF + f0] = ov;
    }
}

// ---------------- W2 -> W2^T bf16 (N x K) ----------------
__global__ void prep_w2t(const float* __restrict__ W2, unsigned short* __restrict__ W2T) {
    int i = blockIdx.x * blockDim.x + threadIdx.x;
    if (i >= FF * FF) return;
    int n = i >> 9, k = i & 511;
    W2T[i] = f2bf(W2[k * FF + n]);
}

// ---------------- W3 -> W3^T bf16, padded to 48 rows ----------------
__global__ void prep_w3t(const float* __restrict__ W3, unsigned short* __restrict__ W3T) {
    int i = blockIdx.x * blockDim.x + threadIdx.x;
    if (i >= 48 * 512) return;
    int n = i >> 9, k = i & 511;
    W3T[i] = (n < F3) ? f2bf(W3[k * F3 + n]) : 0;
}

// ---------------- bf16 MFMA GEMM + fused logits, bf16 output (2-phase dbuf) ---
// 1D grid with L2-affinity swizzle: the 4 n-tiles of one m-tile land 8
// dispatch-slots apart (same XCD under round-robin) so the shared A-tile is
// fetched into that XCD's L2 once instead of 4 L2-misses.
__global__ __launch_bounds__(256) void gemm_mfma(
    const unsigned short* __restrict__ A,   // [MP][K] bf16
    const unsigned short* __restrict__ BT,  // [N][K]  bf16
    const float* __restrict__ a_s, const float* __restrict__ a_d,  // [N]
    unsigned short* __restrict__ Cb,        // [MP][N] bf16
    float* __restrict__ alS, float* __restrict__ alD,              // [MP][HH]
    int N, int K) {
    __shared__ unsigned short As[2][128 * 64];
    __shared__ unsigned short Bs[2][128 * 64];
    int t = threadIdx.x;
    int wave = t >> 6, lane = t & 63;
    int wr = wave >> 1, wc = wave & 1;

    // bijective bid -> (mt, nt): full 32-groups give 8 m x 4 n; tail covers
    // m 384..390 x 4. Same-m blocks are 8 apart in dispatch order.
    int bid = blockIdx.x;
    int mt, nt;
    if (bid < (MT2 / 8) * 32) {
        int g = bid >> 5, r = bid & 31;
        mt = g * 8 + (r & 7);
        nt = r >> 3;
    } else {
        int t2 = bid - (MT2 / 8) * 32;
        mt = (MT2 / 8) * 8 + (t2 >> 2);
        nt = t2 & 3;
    }
    int m0 = mt * 128, n0 = nt * 128;

    f32x4 acc[4][4] = {};
    int kg = lane >> 4;
    int lr = lane & 15;

    auto STAGE = [&](int buf, int k0) {
#pragma unroll
        for (int q = 0; q < 4; ++q) {
            int c   = q * 256 + t;
            int row = c >> 3, kc = c & 7;
            int kcs = kc ^ (row & 7);
            const unsigned short* ga = A + (size_t)(m0 + row) * K + k0 + kcs * 8;
            const unsigned short* gb = BT + (size_t)(n0 + row) * K + k0 + kcs * 8;
            unsigned short* la = &As[buf][(size_t)(q * 256 + wave * 64) * 8];
            unsigned short* lb = &Bs[buf][(size_t)(q * 256 + wave * 64) * 8];
            __builtin_amdgcn_global_load_lds(
                (const __attribute__((address_space(1))) void*)ga,
                (__attribute__((address_space(3))) void*)la, 16, 0, 0);
            __builtin_amdgcn_global_load_lds(
                (const __attribute__((address_space(1))) void*)gb,
                (__attribute__((address_space(3))) void*)lb, 16, 0, 0);
        }
    };

    const int NT = K / 64;
    STAGE(0, 0);
    __syncthreads();
    int cur = 0;
    for (int kt = 0; kt < NT; ++kt) {
        if (kt + 1 < NT) STAGE(cur ^ 1, (kt + 1) * 64);
        const unsigned short* Ac = As[cur];
        const unsigned short* Bc = Bs[cur];
#pragma unroll
        for (int ks = 0; ks < 2; ++ks) {
            bf16x8 af[4], bf[4];
#pragma unroll
            for (int i = 0; i < 4; ++i) {
                int rowa = wr * 64 + i * 16 + lr;
                af[i] = *(const bf16x8*)&Ac[rowa * 64 + (((ks << 2) | kg) ^ (rowa & 7)) * 8];
                int rowb = wc * 64 + i * 16 + lr;
                bf[i] = *(const bf16x8*)&Bc[rowb * 64 + (((ks << 2) | kg) ^ (rowb & 7)) * 8];
            }
#pragma unroll
            for (int i = 0; i < 4; ++i)
#pragma unroll
                for (int j = 0; j < 4; ++j)
                    acc[i][j] = __builtin_amdgcn_mfma_f32_16x16x32_bf16(
                        af[i], bf[j], acc[i][j], 0, 0, 0);
        }
        __syncthreads();   // drains prefetch vmcnt + compute lgkm; buffers swap
        cur ^= 1;
    }

    // ---- fused attention logits: head = n0/64 + wc ----
    int head = (n0 >> 6) + wc;
    float asv[4], adv[4];
#pragma unroll
    for (int j = 0; j < 4; ++j) {
        int cc = n0 + wc * 64 + j * 16 + lr;
        asv[j] = a_s[cc];
        adv[j] = a_d[cc];
    }
#pragma unroll
    for (int i = 0; i < 4; ++i) {
#pragma unroll
        for (int reg = 0; reg < 4; ++reg) {
            float ps = 0.f, pd = 0.f;
#pragma unroll
            for (int j = 0; j < 4; ++j) {
                ps += acc[i][j][reg] * asv[j];
                pd += acc[i][j][reg] * adv[j];
            }
#pragma unroll
            for (int d = 1; d < 16; d <<= 1) {
                ps += __shfl_xor(ps, d);
                pd += __shfl_xor(pd, d);
            }
            if (lr == 0) {
                int r = m0 + wr * 64 + i * 16 + kg * 4 + reg;
                alS[(size_t)r * HH + head] = ps;
                alD[(size_t)r * HH + head] = pd;
            }
        }
    }

#pragma unroll
    for (int i = 0; i < 4; ++i) {
        int rb = m0 + wr * 64 + i * 16 + kg * 4;
#pragma unroll
        for (int j = 0; j < 4; ++j) {
            int cc = n0 + wc * 64 + j * 16 + lr;
#pragma unroll
            for (int reg = 0; reg < 4; ++reg)
                Cb[(size_t)(rb + reg) * N + cc] = f2bf(acc[i][j][reg]);
        }
    }
}

// ---------------- layer-3 MFMA GEMM: h3[MP,40] = A[MP,512] @ W3T[48,512]^T ----
__global__ __launch_bounds__(256) void gemm3_mfma(
    const unsigned short* __restrict__ A,    // [MP][512] bf16
    const unsigned short* __restrict__ BT,   // [48][512] bf16
    float* __restrict__ C) {                 // [NN][40] f32
    __shared__ unsigned short As[128 * 64];
    __shared__ unsigned short Bs[48 * 64];
    int t = threadIdx.x;
    int wave = t >> 6, lane = t & 63;
    int m0 = blockIdx.x * 128;
    int kg = lane >> 4, lr = lane & 15;

    f32x4 acc[2][3] = {};

    for (int k0 = 0; k0 < 512; k0 += 64) {
#pragma unroll
        for (int q = 0; q < 4; ++q) {
            int c   = q * 256 + t;
            int row = c >> 3, kc = c & 7;
            int kcs = kc ^ (row & 7);
            const unsigned short* ga = A + (size_t)(m0 + row) * 512 + k0 + kcs * 8;
            unsigned short* la = &As[(size_t)(q * 256 + wave * 64) * 8];
            __builtin_amdgcn_global_load_lds(
                (const __attribute__((address_space(1))) void*)ga,
                (__attribute__((address_space(3))) void*)la, 16, 0, 0);
        }
        {
            int c   = t;           // chunks 0..255
            int row = c >> 3, kc = c & 7;
            int kcs = kc ^ (row & 7);
            const unsigned short* gb = BT + (size_t)row * 512 + k0 + kcs * 8;
            unsigned short* lb = &Bs[(size_t)(wave * 64) * 8];
            __builtin_amdgcn_global_load_lds(
                (const __attribute__((address_space(1))) void*)gb,
                (__attribute__((address_space(3))) void*)lb, 16, 0, 0);
        }
        if (t < 128) {             // chunks 256..383
            int c   = 256 + t;
            int row = c >> 3, kc = c & 7;
            int kcs = kc ^ (row & 7);
            const unsigned short* gb = BT + (size_t)row * 512 + k0 + kcs * 8;
            unsigned short* lb = &Bs[(size_t)(256 + wave * 64) * 8];
            __builtin_amdgcn_global_load_lds(
                (const __attribute__((address_space(1))) void*)gb,
                (__attribute__((address_space(3))) void*)lb, 16, 0, 0);
        }
        __syncthreads();
#pragma unroll
        for (int ks = 0; ks < 2; ++ks) {
            bf16x8 af[2], bf[3];
#pragma unroll
            for (int i = 0; i < 2; ++i) {
                int rowa = wave * 32 + i * 16 + lr;
                af[i] = *(const bf16x8*)&As[rowa * 64 + (((ks << 2) | kg) ^ (rowa & 7)) * 8];
            }
#pragma unroll
            for (int j = 0; j < 3; ++j) {
                int rowb = j * 16 + lr;
                bf[j] = *(const bf16x8*)&Bs[rowb * 64 + (((ks << 2) | kg) ^ (rowb & 7)) * 8];
            }
#pragma unroll
            for (int i = 0; i < 2; ++i)
#pragma unroll
                for (int j = 0; j < 3; ++j)
                    acc[i][j] = __builtin_amdgcn_mfma_f32_16x16x32_bf16(
                        af[i], bf[j], acc[i][j], 0, 0, 0);
        }
        __syncthreads();
    }

#pragma unroll
    for (int i = 0; i < 2; ++i) {
        int rb = m0 + wave * 32 + i * 16 + kg * 4;
#pragma unroll
        for (int j = 0; j < 3; ++j) {
            int cc = j * 16 + lr;
            if (cc >= F3) continue;
#pragma unroll
            for (int reg = 0; reg < 4; ++reg) {
                int r = rb + reg;
                if (r < NN) C[(size_t)r * F3 + cc] = acc[i][j][reg];
            }
        }
    }
}

// ---------------- layer-3 attention logits (F=40, C=5) ----------------
__global__ void al40_kernel(const float* __restrict__ h3, const float* __restrict__ as3,
                            const float* __restrict__ ad3, float* __restrict__ al_s,
                            float* __restrict__ al_d) {
    int n = blockIdx.x * blockDim.x + threadIdx.x;
    if (n >= NN) return;
#pragma unroll
    for (int hh = 0; hh < HH; ++hh) {
        float s = 0.f, d = 0.f;
#pragma unroll
        for (int c = 0; c < C3; ++c) {
            float v = h3[(size_t)n * F3 + hh * C3 + c];
            s += v * as3[hh * C3 + c];
            d += v * ad3[hh * C3 + c];
        }
        al_s[n * HH + hh] = s;
        al_d[n * HH + hh] = d;
    }
}

// ---------------- layer-3 attention, wave-parallel (4 nodes/block) ------------
__global__ __launch_bounds__(256) void attn3_kernel(
    const float* __restrict__ h3, const float* __restrict__ al_s,
    const float* __restrict__ al_d, const int* __restrict__ offs,
    const int* __restrict__ srcs, const float* __restrict__ b3,
    float* __restrict__ out) {
    __shared__ float alpha_sh[4][MAXE][HH];
    __shared__ int   srcs_sh[4][MAXE];
    __shared__ float idn_sh[4][HH], m_sh[4][HH], ald_sh2[4][HH];
    __shared__ float accs[4][F3];
    __shared__ float vv[4][C3];
    int w = threadIdx.x >> 6, lane = threadIdx.x & 63;
    int n = blockIdx.x * 4 + w;
    int h = lane >> 3, es = lane & 7;
    int beg = offs[n], end = offs[n + 1], deg = end - beg;

    float ald = al_d[n * HH + h];
    float m = -1e30f;
    for (int e = es; e < deg; e += 8) {
        int s = srcs[beg + e];
        float sc = al_s[s * HH + h] + ald;
        sc = sc > 0.f ? sc : 0.2f * sc;
        m = fmaxf(m, sc);
    }
    m = fmaxf(m, __shfl_xor(m, 1));
    m = fmaxf(m, __shfl_xor(m, 2));
    m = fmaxf(m, __shfl_xor(m, 4));
    float den = 0.f;
    for (int e = es; e < deg; e += 8) {
        int s = srcs[beg + e];
        if (h == 0 && e < MAXE) srcs_sh[w][e] = s;
        float sc = al_s[s * HH + h] + ald;
        sc = sc > 0.f ? sc : 0.2f * sc;
        float ex = __expf(sc - m);
        den += ex;
        if (e < MAXE) alpha_sh[w][e][h] = ex;
    }
    den += __shfl_xor(den, 1);
    den += __shfl_xor(den, 2);
    den += __shfl_xor(den, 4);
    float idn = 1.f / (den + 1e-16f);
    if (es == 0) { idn_sh[w][h] = idn; m_sh[w][h] = m; ald_sh2[w][h] = ald; }
    __syncthreads();

    if (lane < F3) {
        int hh = lane / C3;
        float acc = 0.f;
        if (deg <= MAXE) {
            for (int e = 0; e < deg; ++e) {
                int s = srcs_sh[w][e];
                acc += alpha_sh[w][e][hh] * h3[(size_t)s * F3 + lane];
            }
        } else {
            float mm = m_sh[w][hh], aald = ald_sh2[w][hh];
            for (int e = 0; e < deg; ++e) {
                int s = srcs[beg + e];
                float sc = al_s[s * HH + hh] + aald;
                sc = sc > 0.f ? sc : 0.2f * sc;
                acc += __expf(sc - mm) * h3[(size_t)s * F3 + lane];
            }
        }
        accs[w][lane] = acc * idn_sh[w][hh];
    }
    __syncthreads();
    if (lane < C3) {
        float s = 0.f;
#pragma unroll
        for (int hh = 0; hh < HH; ++hh) s += accs[w][hh * C3 + lane];
        vv[w][lane] = s * 0.125f + b3[lane];
    }
    __syncthreads();
    if (lane < C3) {
        float mx = vv[w][0];
#pragma unroll
        for (int c = 1; c < C3; ++c) mx = fmaxf(mx, vv[w][c]);
        float se = 0.f;
#pragma unroll
        for (int c = 0; c < C3; ++c) se += __expf(vv[w][c] - mx);
        out[(size_t)n * C3 + lane] = vv[w][lane] - mx - logf(se);
    }
}

// ---------------- host launcher ----------------
extern "C" void kernel_launch(void* const* d_in, const int* in_sizes, int n_in,
                              void* d_out, int out_size, void* d_ws, size_t ws_size,
                              hipStream_t stream) {
    const float* x   = (const float*)d_in[0];
    const int*   ei  = (const int*)d_in[1];
    const float* W1  = (const float*)d_in[2];
    const float* as1 = (const float*)d_in[3];
    const float* ad1 = (const float*)d_in[4];
    const float* b1  = (const float*)d_in[5];
    const float* W2  = (const float*)d_in[6];
    const float* as2 = (const float*)d_in[7];
    const float* ad2 = (const float*)d_in[8];
    const float* b2  = (const float*)d_in[9];
    const float* W3  = (const float*)d_in[10];
    const float* as3 = (const float*)d_in[11];
    const float* ad3 = (const float*)d_in[12];
    const float* b3  = (const float*)d_in[13];
    float* out = (float*)d_out;

    // ---- workspace layout (lifetime-aliased, ~118 MB) ----
    auto au = [](size_t v) { return (v + 255) & ~(size_t)255; };
    char* p = (char*)d_ws;
    size_t szHb = au((size_t)MP * FF * 2);           // 51.25 MB
    char* r1 = p;
    unsigned short* Hb1 = (unsigned short*)r1;
    unsigned short* Hb2 = (unsigned short*)r1;
    p += szHb;
    char* r2 = p;
    unsigned short* A2   = (unsigned short*)r2;
    unsigned short* Bb16 = (unsigned short*)r2;      // alias: attn2 out
    unsigned short* W2T  = (unsigned short*)(r2 + szHb);
    p = r2 + szHb + au((size_t)FF * FF * 2);
    unsigned short* W3T = (unsigned short*)p;  p += au((size_t)48 * 512 * 2);
    float* alS  = (float*)p;  p += au((size_t)MP * HH * 4);
    float* alD  = (float*)p;  p += au((size_t)MP * HH * 4);
    float* h3   = (float*)p;  p += au((size_t)NN * F3 * 4);
    int* offs   = (int*)p;    p += au((size_t)(NN + 1) * 4);
    int* cnt    = (int*)p;    p += au((size_t)NN * 4);
    int* srcs   = (int*)p;    p += au((size_t)ETOT * 4);
    int* bsum   = (int*)p;    p += au(64 * 4);

    // ---- CSR build (dst-sorted) + prep ----
    hipMemsetAsync(cnt, 0, (size_t)NN * 4, stream);
    count_kernel<<<(ETOT + 255) / 256, 256, 0, stream>>>(ei, cnt);
    scan_blocks<<<NBLK, 1024, 0, stream>>>(cnt, offs, bsum);
    scan_sums<<<1, 64, 0, stream>>>(bsum);
    scan_add<<<NBLK, 1024, 0, stream>>>(offs, bsum);
    hipMemsetAsync(cnt, 0, (size_t)NN * 4, stream);
    scatter_kernel<<<(ETOT + 255) / 256, 256, 0, stream>>>(ei, offs, cnt, srcs);
    hipMemsetAsync(A2 + (size_t)NN * FF, 0, (size_t)(MP - NN) * FF * 2, stream);
    prep_w2t<<<(FF * FF + 255) / 256, 256, 0, stream>>>(W2, W2T);
    prep_w3t<<<(48 * 512 + 255) / 256, 256, 0, stream>>>(W3, W3T);

    // ---- layer 1 ----
    gemm1_fused<<<(NN + 63) / 64, 256, 0, stream>>>(x, W1, as1, ad1, Hb1, alS, alD);
    attn_gather<<<(NN + 3) / 4, 256, 0, stream>>>(Hb1, alS, alD, offs, srcs, b1,
                                                  nullptr, A2, 1);

    // ---- layer 2: bf16 MFMA GEMM (+ fused logits), dbuf + L2-affinity swizzle
    gemm_mfma<<<GT2, 256, 0, stream>>>(
        A2, W2T, as2, ad2, Hb2, alS, alD, FF, FF);
    attn_gather<<<(NN + 3) / 4, 256, 0, stream>>>(Hb2, alS, alD, offs, srcs, b2,
                                                  nullptr, Bb16, 1);

    // ---- layer 3 ----
    gemm3_mfma<<<MP / 128, 256, 0, stream>>>(Bb16, W3T, h3);
    al40_kernel<<<(NN + 255) / 256, 256, 0, stream>>>(h3, as3, ad3, alS, alD);
    attn3_kernel<<<NN / 4, 256, 0, stream>>>(h3, alS, alD, offs, srcs, b3, out);
}

// Round 10
// 351.588 us; speedup vs baseline: 4.6357x; 1.0254x over previous
//
#include <hip/hip_runtime.h>
#include <hip/hip_bf16.h>

#define NN    50000   // nodes
#define MP    50048   // padded to 128*391 for MFMA GEMM
#define E0C   400000  // raw edges
#define ETOT  450000  // + self loops
#define HH    8
#define FF    512     // H*C layers 1-2
#define F3    40      // H*C3 layer 3
#define C3    5
#define MAXE  128     // LDS alpha-cache capacity (deg ~ Poisson(8)+1)
#define NBLK  ((NN + 1023) / 1024)   // 49 scan blocks
#define MT2   (MP / 128)             // 391 m-tiles layer-2 gemm
#define GT2   (MT2 * 4)              // 1564 blocks

typedef __attribute__((ext_vector_type(8))) short bf16x8;
typedef __attribute__((ext_vector_type(8))) short s16x8;
typedef __attribute__((ext_vector_type(4))) float f32x4;

__device__ inline unsigned short f2bf(float f) {
    union { float f; unsigned int u; } v; v.f = f;
    unsigned int r = v.u + 0x7FFF + ((v.u >> 16) & 1);
    return (unsigned short)(r >> 16);
}
__device__ inline float bf2f(unsigned short u) {
    union { unsigned int i; float f; } v; v.i = ((unsigned int)u) << 16;
    return v.f;
}

// ---------------- CSR build ----------------
__global__ void count_kernel(const int* __restrict__ ei, int* __restrict__ cnt) {
    int e = blockIdx.x * blockDim.x + threadIdx.x;
    if (e >= ETOT) return;
    int dst = (e < E0C) ? ei[E0C + e] : (e - E0C);
    atomicAdd(&cnt[dst], 1);
}

__global__ __launch_bounds__(1024) void scan_blocks(const int* __restrict__ cnt,
                                                    int* __restrict__ offs,
                                                    int* __restrict__ bsum) {
    __shared__ int s[1024];
    int tid = threadIdx.x;
    int i = blockIdx.x * 1024 + tid;
    s[tid] = (i < NN) ? cnt[i] : 0;
    __syncthreads();
    for (int d = 1; d < 1024; d <<= 1) {
        int add = (tid >= d) ? s[tid - d] : 0;
        __syncthreads();
        s[tid] += add;
        __syncthreads();
    }
    if (i < NN) offs[i + 1] = s[tid];
    if (tid == 1023) bsum[blockIdx.x] = s[1023];
}

__global__ __launch_bounds__(64) void scan_sums(int* __restrict__ bsum) {
    int lane = threadIdx.x;
    int v = (lane < NBLK) ? bsum[lane] : 0;
    int orig = v;
#pragma unroll
    for (int d = 1; d < 64; d <<= 1) {
        int o = __shfl_up(v, d);
        if (lane >= d) v += o;
    }
    if (lane < NBLK) bsum[lane] = v - orig;   // exclusive prefix
}

__global__ __launch_bounds__(1024) void scan_add(int* __restrict__ offs,
                                                 const int* __restrict__ bsum) {
    int i = blockIdx.x * 1024 + threadIdx.x;
    if (i < NN) offs[i + 1] += bsum[blockIdx.x];
    if (i == 0) offs[0] = 0;
}

__global__ void scatter_kernel(const int* __restrict__ ei, const int* __restrict__ offs,
                               int* __restrict__ cur, int* __restrict__ srcs) {
    int e = blockIdx.x * blockDim.x + threadIdx.x;
    if (e >= ETOT) return;
    int src, dst;
    if (e < E0C) { src = ei[e]; dst = ei[E0C + e]; }
    else         { src = dst = e - E0C; }
    int pos = offs[dst] + atomicAdd(&cur[dst], 1);
    srcs[pos] = src;
}

// ---------------- layer 1 GEMM (K=12) fused with logits, 64 nodes/block ------
__global__ __launch_bounds__(256) void gemm1_fused(
    const float* __restrict__ x, const float* __restrict__ W1,
    const float* __restrict__ as1, const float* __restrict__ ad1,
    unsigned short* __restrict__ hb, float* __restrict__ al_s,
    float* __restrict__ al_d) {
    __shared__ float xs[64 * 12];
    int t = threadIdx.x;
    int n0 = blockIdx.x * 64;
    int nvalid = NN - n0; if (nvalid > 64) nvalid = 64;

    for (int j = t; j < nvalid * 12; j += 256) xs[j] = x[(size_t)n0 * 12 + j];
    __syncthreads();

    int f = t * 2;
    float w0[12], w1[12];
#pragma unroll
    for (int k = 0; k < 12; ++k) {
        float2 wv = *(const float2*)&W1[k * FF + f];
        w0[k] = wv.x; w1[k] = wv.y;
    }
    float2 asv = *(const float2*)&as1[f];
    float2 adv = *(const float2*)&ad1[f];
    int head = t >> 5;

    for (int ni = 0; ni < nvalid; ++ni) {
        const float* xp = &xs[ni * 12];
        float4 xa = *(const float4*)xp;
        float4 xb = *(const float4*)(xp + 4);
        float4 xc = *(const float4*)(xp + 8);
        float xv[12] = {xa.x, xa.y, xa.z, xa.w, xb.x, xb.y, xb.z, xb.w,
                        xc.x, xc.y, xc.z, xc.w};
        float h0 = 0.f, h1 = 0.f;
#pragma unroll
        for (int k = 0; k < 12; ++k) { h0 += xv[k] * w0[k]; h1 += xv[k] * w1[k]; }
        unsigned int u = ((unsigned int)f2bf(h1) << 16) | f2bf(h0);
        *(unsigned int*)&hb[(size_t)(n0 + ni) * FF + f] = u;
        float ps = h0 * asv.x + h1 * asv.y;
        float pd = h0 * adv.x + h1 * adv.y;
#pragma unroll
        for (int d = 1; d < 32; d <<= 1) {
            ps += __shfl_xor(ps, d);
            pd += __shfl_xor(pd, d);
        }
        if ((t & 31) == 0) {
            al_s[(size_t)(n0 + ni) * HH + head] = ps;
            al_d[(size_t)(n0 + ni) * HH + head] = pd;
        }
    }
}

// ---------------- attention aggregate: ONE WAVE PER NODE, bf16 gather ----------
// Softmax: pass A caches sc in LDS (one global dep-chain), pass B is LDS-only.
// Normalization deferred to acc *= idn. Gather: 4 row-loads in flight.
__global__ __launch_bounds__(256) void attn_gather(
    const unsigned short* __restrict__ Hb,   // [*,FF] bf16
    const float* __restrict__ alS, const float* __restrict__ alD,
    const int* __restrict__ offs, const int* __restrict__ srcs,
    const float* __restrict__ bias,
    float* __restrict__ out_f32, unsigned short* __restrict__ out_b16, int relu) {
    __shared__ float alpha_sh[4][MAXE][HH];
    __shared__ int   srcs_sh[4][MAXE];
    int w = threadIdx.x >> 6, lane = threadIdx.x & 63;
    int n = blockIdx.x * 4 + w;
    if (n >= NN) return;
    int h = lane >> 3, es = lane & 7;
    int beg = offs[n], end = offs[n + 1], deg = end - beg;

    float ald = alD[n * HH + h];
    float m = -1e30f, den = 0.f, idn;

    if (deg <= MAXE) {
        // pass A: sc -> LDS + running max (single global dependent chain)
        for (int e = es; e < deg; e += 8) {
            int s = srcs[beg + e];
            if (h == 0) srcs_sh[w][e] = s;
            float sc = alS[s * HH + h] + ald;
            sc = sc > 0.f ? sc : 0.2f * sc;
            alpha_sh[w][e][h] = sc;
            m = fmaxf(m, sc);
        }
        m = fmaxf(m, __shfl_xor(m, 1));
        m = fmaxf(m, __shfl_xor(m, 2));
        m = fmaxf(m, __shfl_xor(m, 4));
        // pass B: exp from LDS, denom
        for (int e = es; e < deg; e += 8) {
            float ex = __expf(alpha_sh[w][e][h] - m);
            den += ex;
            alpha_sh[w][e][h] = ex;
        }
        den += __shfl_xor(den, 1);
        den += __shfl_xor(den, 2);
        den += __shfl_xor(den, 4);
        idn = 1.f / (den + 1e-16f);
    } else {
        for (int e = es; e < deg; e += 8) {
            int s = srcs[beg + e];
            float sc = alS[s * HH + h] + ald;
            sc = sc > 0.f ? sc : 0.2f * sc;
            m = fmaxf(m, sc);
        }
        m = fmaxf(m, __shfl_xor(m, 1));
        m = fmaxf(m, __shfl_xor(m, 2));
        m = fmaxf(m, __shfl_xor(m, 4));
        for (int e = es; e < deg; e += 8) {
            int s = srcs[beg + e];
            float sc = alS[s * HH + h] + ald;
            sc = sc > 0.f ? sc : 0.2f * sc;
            den += __expf(sc - m);
        }
        den += __shfl_xor(den, 1);
        den += __shfl_xor(den, 2);
        den += __shfl_xor(den, 4);
        idn = 1.f / (den + 1e-16f);
    }

    // phase 2: gather (lane feature block f0..f0+7, head h), 4 loads in flight
    int f0 = lane * 8;
    float acc[8] = {};
    if (deg <= MAXE) {
        int e = 0;
        for (; e + 4 <= deg; e += 4) {
            int s0 = srcs_sh[w][e + 0], s1 = srcs_sh[w][e + 1];
            int s2 = srcs_sh[w][e + 2], s3 = srcs_sh[w][e + 3];
            bf16x8 v0 = *(const bf16x8*)&Hb[(size_t)s0 * FF + f0];
            bf16x8 v1 = *(const bf16x8*)&Hb[(size_t)s1 * FF + f0];
            bf16x8 v2 = *(const bf16x8*)&Hb[(size_t)s2 * FF + f0];
            bf16x8 v3 = *(const bf16x8*)&Hb[(size_t)s3 * FF + f0];
            float a0 = alpha_sh[w][e + 0][h], a1 = alpha_sh[w][e + 1][h];
            float a2 = alpha_sh[w][e + 2][h], a3 = alpha_sh[w][e + 3][h];
#pragma unroll
            for (int k = 0; k < 8; ++k) {
                acc[k] += a0 * bf2f((unsigned short)v0[k]);
                acc[k] += a1 * bf2f((unsigned short)v1[k]);
                acc[k] += a2 * bf2f((unsigned short)v2[k]);
                acc[k] += a3 * bf2f((unsigned short)v3[k]);
            }
        }
        for (; e < deg; ++e) {
            int s = srcs_sh[w][e];
            float a = alpha_sh[w][e][h];
            bf16x8 v = *(const bf16x8*)&Hb[(size_t)s * FF + f0];
#pragma unroll
            for (int k = 0; k < 8; ++k)
                acc[k] += a * bf2f((unsigned short)v[k]);
        }
#pragma unroll
        for (int k = 0; k < 8; ++k) acc[k] *= idn;
    } else {
        for (int e = 0; e < deg; ++e) {
            int s = srcs[beg + e];
            float sc = alS[s * HH + h] + ald;
            sc = sc > 0.f ? sc : 0.2f * sc;
            float a = __expf(sc - m) * idn;
            bf16x8 v = *(const bf16x8*)&Hb[(size_t)s * FF + f0];
#pragma unroll
            for (int k = 0; k < 8; ++k)
                acc[k] += a * bf2f((unsigned short)v[k]);
        }
    }
    float4 b0 = *(const float4*)&bias[f0];
    float4 b1 = *(const float4*)&bias[f0 + 4];
    float bv[8] = {b0.x, b0.y, b0.z, b0.w, b1.x, b1.y, b1.z, b1.w};
    float vv[8];
#pragma unroll
    for (int k = 0; k < 8; ++k) {
        float t = acc[k] + bv[k];
        vv[k] = relu ? fmaxf(t, 0.f) : t;
    }
    if (out_f32) {
        float4 o0 = {vv[0], vv[1], vv[2], vv[3]};
        float4 o1 = {vv[4], vv[5], vv[6], vv[7]};
        *(float4*)&out_f32[(size_t)n * FF + f0] = o0;
        *(float4*)&out_f32[(size_t)n * FF + f0 + 4] = o1;
    }
    if (out_b16) {
        s16x8 ov;
#pragma unroll
        for (int k = 0; k < 8; ++k) ov[k] = (short)f2bf(vv[k]);
        *(s16x8*)&out_b16[(size_t)n * FF + f0] = ov;
    }
}

// ---------------- W2 -> W2^T bf16 (N x K) ----------------
__global__ void prep_w2t(const float* __restrict__ W2, unsigned short* __restrict__ W2T) {
    int i = blockIdx.x * blockDim.x + threadIdx.x;
    if (i >= FF * FF) return;
    int n = i >> 9, k = i & 511;
    W2T[i] = f2bf(W2[k * FF + n]);
}

// ---------------- W3 -> W3^T bf16, padded to 48 rows ----------------
__global__ void prep_w3t(const float* __restrict__ W3, unsigned short* __restrict__ W3T) {
    int i = blockIdx.x * blockDim.x + threadIdx.x;
    if (i >= 48 * 512) return;
    int n = i >> 9, k = i & 511;
    W3T[i] = (n < F3) ? f2bf(W3[k * F3 + n]) : 0;
}

// ---------------- bf16 MFMA GEMM + fused logits, bf16 output (2-phase dbuf) ---
__global__ __launch_bounds__(256) void gemm_mfma(
    const unsigned short* __restrict__ A,   // [MP][K] bf16
    const unsigned short* __restrict__ BT,  // [N][K]  bf16
    const float* __restrict__ a_s, const float* __restrict__ a_d,  // [N]
    unsigned short* __restrict__ Cb,        // [MP][N] bf16
    float* __restrict__ alS, float* __restrict__ alD,              // [MP][HH]
    int N, int K) {
    __shared__ unsigned short As[2][128 * 64];
    __shared__ unsigned short Bs[2][128 * 64];
    int t = threadIdx.x;
    int wave = t >> 6, lane = t & 63;
    int wr = wave >> 1, wc = wave & 1;

    // bijective bid -> (mt, nt): same-m blocks 8 apart in dispatch order.
    int bid = blockIdx.x;
    int mt, nt;
    if (bid < (MT2 / 8) * 32) {
        int g = bid >> 5, r = bid & 31;
        mt = g * 8 + (r & 7);
        nt = r >> 3;
    } else {
        int t2 = bid - (MT2 / 8) * 32;
        mt = (MT2 / 8) * 8 + (t2 >> 2);
        nt = t2 & 3;
    }
    int m0 = mt * 128, n0 = nt * 128;

    f32x4 acc[4][4] = {};
    int kg = lane >> 4;
    int lr = lane & 15;

    auto STAGE = [&](int buf, int k0) {
#pragma unroll
        for (int q = 0; q < 4; ++q) {
            int c   = q * 256 + t;
            int row = c >> 3, kc = c & 7;
            int kcs = kc ^ (row & 7);
            const unsigned short* ga = A + (size_t)(m0 + row) * K + k0 + kcs * 8;
            const unsigned short* gb = BT + (size_t)(n0 + row) * K + k0 + kcs * 8;
            unsigned short* la = &As[buf][(size_t)(q * 256 + wave * 64) * 8];
            unsigned short* lb = &Bs[buf][(size_t)(q * 256 + wave * 64) * 8];
            __builtin_amdgcn_global_load_lds(
                (const __attribute__((address_space(1))) void*)ga,
                (__attribute__((address_space(3))) void*)la, 16, 0, 0);
            __builtin_amdgcn_global_load_lds(
                (const __attribute__((address_space(1))) void*)gb,
                (__attribute__((address_space(3))) void*)lb, 16, 0, 0);
        }
    };

    const int NT = K / 64;
    STAGE(0, 0);
    __syncthreads();
    int cur = 0;
    for (int kt = 0; kt < NT; ++kt) {
        if (kt + 1 < NT) STAGE(cur ^ 1, (kt + 1) * 64);
        const unsigned short* Ac = As[cur];
        const unsigned short* Bc = Bs[cur];
#pragma unroll
        for (int ks = 0; ks < 2; ++ks) {
            bf16x8 af[4], bf[4];
#pragma unroll
            for (int i = 0; i < 4; ++i) {
                int rowa = wr * 64 + i * 16 + lr;
                af[i] = *(const bf16x8*)&Ac[rowa * 64 + (((ks << 2) | kg) ^ (rowa & 7)) * 8];
                int rowb = wc * 64 + i * 16 + lr;
                bf[i] = *(const bf16x8*)&Bc[rowb * 64 + (((ks << 2) | kg) ^ (rowb & 7)) * 8];
            }
#pragma unroll
            for (int i = 0; i < 4; ++i)
#pragma unroll
                for (int j = 0; j < 4; ++j)
                    acc[i][j] = __builtin_amdgcn_mfma_f32_16x16x32_bf16(
                        af[i], bf[j], acc[i][j], 0, 0, 0);
        }
        __syncthreads();   // drains prefetch vmcnt + compute lgkm; buffers swap
        cur ^= 1;
    }

    // ---- fused attention logits: head = n0/64 + wc ----
    int head = (n0 >> 6) + wc;
    float asv[4], adv[4];
#pragma unroll
    for (int j = 0; j < 4; ++j) {
        int cc = n0 + wc * 64 + j * 16 + lr;
        asv[j] = a_s[cc];
        adv[j] = a_d[cc];
    }
#pragma unroll
    for (int i = 0; i < 4; ++i) {
#pragma unroll
        for (int reg = 0; reg < 4; ++reg) {
            float ps = 0.f, pd = 0.f;
#pragma unroll
            for (int j = 0; j < 4; ++j) {
                ps += acc[i][j][reg] * asv[j];
                pd += acc[i][j][reg] * adv[j];
            }
#pragma unroll
            for (int d = 1; d < 16; d <<= 1) {
                ps += __shfl_xor(ps, d);
                pd += __shfl_xor(pd, d);
            }
            if (lr == 0) {
                int r = m0 + wr * 64 + i * 16 + kg * 4 + reg;
                alS[(size_t)r * HH + head] = ps;
                alD[(size_t)r * HH + head] = pd;
            }
        }
    }

#pragma unroll
    for (int i = 0; i < 4; ++i) {
        int rb = m0 + wr * 64 + i * 16 + kg * 4;
#pragma unroll
        for (int j = 0; j < 4; ++j) {
            int cc = n0 + wc * 64 + j * 16 + lr;
#pragma unroll
            for (int reg = 0; reg < 4; ++reg)
                Cb[(size_t)(rb + reg) * N + cc] = f2bf(acc[i][j][reg]);
        }
    }
}

// ---------------- layer-3 MFMA GEMM: h3[MP,40] = A[MP,512] @ W3T[48,512]^T ----
__global__ __launch_bounds__(256) void gemm3_mfma(
    const unsigned short* __restrict__ A,    // [MP][512] bf16
    const unsigned short* __restrict__ BT,   // [48][512] bf16
    float* __restrict__ C) {                 // [NN][40] f32
    __shared__ unsigned short As[128 * 64];
    __shared__ unsigned short Bs[48 * 64];
    int t = threadIdx.x;
    int wave = t >> 6, lane = t & 63;
    int m0 = blockIdx.x * 128;
    int kg = lane >> 4, lr = lane & 15;

    f32x4 acc[2][3] = {};

    for (int k0 = 0; k0 < 512; k0 += 64) {
#pragma unroll
        for (int q = 0; q < 4; ++q) {
            int c   = q * 256 + t;
            int row = c >> 3, kc = c & 7;
            int kcs = kc ^ (row & 7);
            const unsigned short* ga = A + (size_t)(m0 + row) * 512 + k0 + kcs * 8;
            unsigned short* la = &As[(size_t)(q * 256 + wave * 64) * 8];
            __builtin_amdgcn_global_load_lds(
                (const __attribute__((address_space(1))) void*)ga,
                (__attribute__((address_space(3))) void*)la, 16, 0, 0);
        }
        {
            int c   = t;           // chunks 0..255
            int row = c >> 3, kc = c & 7;
            int kcs = kc ^ (row & 7);
            const unsigned short* gb = BT + (size_t)row * 512 + k0 + kcs * 8;
            unsigned short* lb = &Bs[(size_t)(wave * 64) * 8];
            __builtin_amdgcn_global_load_lds(
                (const __attribute__((address_space(1))) void*)gb,
                (__attribute__((address_space(3))) void*)lb, 16, 0, 0);
        }
        if (t < 128) {             // chunks 256..383
            int c   = 256 + t;
            int row = c >> 3, kc = c & 7;
            int kcs = kc ^ (row & 7);
            const unsigned short* gb = BT + (size_t)row * 512 + k0 + kcs * 8;
            unsigned short* lb = &Bs[(size_t)(256 + wave * 64) * 8];
            __builtin_amdgcn_global_load_lds(
                (const __attribute__((address_space(1))) void*)gb,
                (__attribute__((address_space(3))) void*)lb, 16, 0, 0);
        }
        __syncthreads();
#pragma unroll
        for (int ks = 0; ks < 2; ++ks) {
            bf16x8 af[2], bf[3];
#pragma unroll
            for (int i = 0; i < 2; ++i) {
                int rowa = wave * 32 + i * 16 + lr;
                af[i] = *(const bf16x8*)&As[rowa * 64 + (((ks << 2) | kg) ^ (rowa & 7)) * 8];
            }
#pragma unroll
            for (int j = 0; j < 3; ++j) {
                int rowb = j * 16 + lr;
                bf[j] = *(const bf16x8*)&Bs[rowb * 64 + (((ks << 2) | kg) ^ (rowb & 7)) * 8];
            }
#pragma unroll
            for (int i = 0; i < 2; ++i)
#pragma unroll
                for (int j = 0; j < 3; ++j)
                    acc[i][j] = __builtin_amdgcn_mfma_f32_16x16x32_bf16(
                        af[i], bf[j], acc[i][j], 0, 0, 0);
        }
        __syncthreads();
    }

#pragma unroll
    for (int i = 0; i < 2; ++i) {
        int rb = m0 + wave * 32 + i * 16 + kg * 4;
#pragma unroll
        for (int j = 0; j < 3; ++j) {
            int cc = j * 16 + lr;
            if (cc >= F3) continue;
#pragma unroll
            for (int reg = 0; reg < 4; ++reg) {
                int r = rb + reg;
                if (r < NN) C[(size_t)r * F3 + cc] = acc[i][j][reg];
            }
        }
    }
}

// ---------------- layer-3 attention logits (F=40, C=5) ----------------
__global__ void al40_kernel(const float* __restrict__ h3, const float* __restrict__ as3,
                            const float* __restrict__ ad3, float* __restrict__ al_s,
                            float* __restrict__ al_d) {
    int n = blockIdx.x * blockDim.x + threadIdx.x;
    if (n >= NN) return;
#pragma unroll
    for (int hh = 0; hh < HH; ++hh) {
        float s = 0.f, d = 0.f;
#pragma unroll
        for (int c = 0; c < C3; ++c) {
            float v = h3[(size_t)n * F3 + hh * C3 + c];
            s += v * as3[hh * C3 + c];
            d += v * ad3[hh * C3 + c];
        }
        al_s[n * HH + hh] = s;
        al_d[n * HH + hh] = d;
    }
}

// ---------------- layer-3 attention, wave-parallel (4 nodes/block) ------------
__global__ __launch_bounds__(256) void attn3_kernel(
    const float* __restrict__ h3, const float* __restrict__ al_s,
    const float* __restrict__ al_d, const int* __restrict__ offs,
    const int* __restrict__ srcs, const float* __restrict__ b3,
    float* __restrict__ out) {
    __shared__ float alpha_sh[4][MAXE][HH];
    __shared__ int   srcs_sh[4][MAXE];
    __shared__ float idn_sh[4][HH], m_sh[4][HH], ald_sh2[4][HH];
    __shared__ float accs[4][F3];
    __shared__ float vv[4][C3];
    int w = threadIdx.x >> 6, lane = threadIdx.x & 63;
    int n = blockIdx.x * 4 + w;
    int h = lane >> 3, es = lane & 7;
    int beg = offs[n], end = offs[n + 1], deg = end - beg;

    float ald = al_d[n * HH + h];
    float m = -1e30f, den = 0.f, idn;
    if (deg <= MAXE) {
        for (int e = es; e < deg; e += 8) {
            int s = srcs[beg + e];
            if (h == 0) srcs_sh[w][e] = s;
            float sc = al_s[s * HH + h] + ald;
            sc = sc > 0.f ? sc : 0.2f * sc;
            alpha_sh[w][e][h] = sc;
            m = fmaxf(m, sc);
        }
        m = fmaxf(m, __shfl_xor(m, 1));
        m = fmaxf(m, __shfl_xor(m, 2));
        m = fmaxf(m, __shfl_xor(m, 4));
        for (int e = es; e < deg; e += 8) {
            float ex = __expf(alpha_sh[w][e][h] - m);
            den += ex;
            alpha_sh[w][e][h] = ex;
        }
        den += __shfl_xor(den, 1);
        den += __shfl_xor(den, 2);
        den += __shfl_xor(den, 4);
        idn = 1.f / (den + 1e-16f);
        if (es == 0) idn_sh[w][h] = idn;
    } else {
        for (int e = es; e < deg; e += 8) {
            int s = srcs[beg + e];
            float sc = al_s[s * HH + h] + ald;
            sc = sc > 0.f ? sc : 0.2f * sc;
            m = fmaxf(m, sc);
        }
        m = fmaxf(m, __shfl_xor(m, 1));
        m = fmaxf(m, __shfl_xor(m, 2));
        m = fmaxf(m, __shfl_xor(m, 4));
        for (int e = es; e < deg; e += 8) {
            int s = srcs[beg + e];
            float sc = al_s[s * HH + h] + ald;
            sc = sc > 0.f ? sc : 0.2f * sc;
            den += __expf(sc - m);
        }
        den += __shfl_xor(den, 1);
        den += __shfl_xor(den, 2);
        den += __shfl_xor(den, 4);
        idn = 1.f / (den + 1e-16f);
        if (es == 0) { idn_sh[w][h] = idn; m_sh[w][h] = m; ald_sh2[w][h] = ald; }
    }
    __syncthreads();

    if (lane < F3) {
        int hh = lane / C3;
        float acc = 0.f;
        if (deg <= MAXE) {
            int e = 0;
            for (; e + 4 <= deg; e += 4) {
                int s0 = srcs_sh[w][e + 0], s1 = srcs_sh[w][e + 1];
                int s2 = srcs_sh[w][e + 2], s3 = srcs_sh[w][e + 3];
                float v0 = h3[(size_t)s0 * F3 + lane];
                float v1 = h3[(size_t)s1 * F3 + lane];
                float v2 = h3[(size_t)s2 * F3 + lane];
                float v3 = h3[(size_t)s3 * F3 + lane];
                acc += alpha_sh[w][e + 0][hh] * v0 + alpha_sh[w][e + 1][hh] * v1
                     + alpha_sh[w][e + 2][hh] * v2 + alpha_sh[w][e + 3][hh] * v3;
            }
            for (; e < deg; ++e) {
                int s = srcs_sh[w][e];
                acc += alpha_sh[w][e][hh] * h3[(size_t)s * F3 + lane];
            }
        } else {
            float mm = m_sh[w][hh], aald = ald_sh2[w][hh];
            for (int e = 0; e < deg; ++e) {
                int s = srcs[beg + e];
                float sc = al_s[s * HH + hh] + aald;
                sc = sc > 0.f ? sc : 0.2f * sc;
                acc += __expf(sc - mm) * h3[(size_t)s * F3 + lane];
            }
        }
        accs[w][lane] = acc * idn_sh[w][hh];
    }
    __syncthreads();
    if (lane < C3) {
        float s = 0.f;
#pragma unroll
        for (int hh = 0; hh < HH; ++hh) s += accs[w][hh * C3 + lane];
        vv[w][lane] = s * 0.125f + b3[lane];
    }
    __syncthreads();
    if (lane < C3) {
        float mx = vv[w][0];
#pragma unroll
        for (int c = 1; c < C3; ++c) mx = fmaxf(mx, vv[w][c]);
        float se = 0.f;
#pragma unroll
        for (int c = 0; c < C3; ++c) se += __expf(vv[w][c] - mx);
        out[(size_t)n * C3 + lane] = vv[w][lane] - mx - logf(se);
    }
}

// ---------------- host launcher ----------------
extern "C" void kernel_launch(void* const* d_in, const int* in_sizes, int n_in,
                              void* d_out, int out_size, void* d_ws, size_t ws_size,
                              hipStream_t stream) {
    const float* x   = (const float*)d_in[0];
    const int*   ei  = (const int*)d_in[1];
    const float* W1  = (const float*)d_in[2];
    const float* as1 = (const float*)d_in[3];
    const float* ad1 = (const float*)d_in[4];
    const float* b1  = (const float*)d_in[5];
    const float* W2  = (const float*)d_in[6];
    const float* as2 = (const float*)d_in[7];
    const float* ad2 = (const float*)d_in[8];
    const float* b2  = (const float*)d_in[9];
    const float* W3  = (const float*)d_in[10];
    const float* as3 = (const float*)d_in[11];
    const float* ad3 = (const float*)d_in[12];
    const float* b3  = (const float*)d_in[13];
    float* out = (float*)d_out;

    // ---- workspace layout (lifetime-aliased, ~118 MB) ----
    auto au = [](size_t v) { return (v + 255) & ~(size_t)255; };
    char* p = (char*)d_ws;
    size_t szHb = au((size_t)MP * FF * 2);           // 51.25 MB
    char* r1 = p;
    unsigned short* Hb1 = (unsigned short*)r1;
    unsigned short* Hb2 = (unsigned short*)r1;
    p += szHb;
    char* r2 = p;
    unsigned short* A2   = (unsigned short*)r2;
    unsigned short* Bb16 = (unsigned short*)r2;      // alias: attn2 out
    unsigned short* W2T  = (unsigned short*)(r2 + szHb);
    p = r2 + szHb + au((size_t)FF * FF * 2);
    unsigned short* W3T = (unsigned short*)p;  p += au((size_t)48 * 512 * 2);
    float* alS  = (float*)p;  p += au((size_t)MP * HH * 4);
    float* alD  = (float*)p;  p += au((size_t)MP * HH * 4);
    float* h3   = (float*)p;  p += au((size_t)NN * F3 * 4);
    int* offs   = (int*)p;    p += au((size_t)(NN + 1) * 4);
    int* cnt    = (int*)p;    p += au((size_t)NN * 4);
    int* srcs   = (int*)p;    p += au((size_t)ETOT * 4);
    int* bsum   = (int*)p;    p += au(64 * 4);

    // ---- CSR build (dst-sorted) + prep ----
    hipMemsetAsync(cnt, 0, (size_t)NN * 4, stream);
    count_kernel<<<(ETOT + 255) / 256, 256, 0, stream>>>(ei, cnt);
    scan_blocks<<<NBLK, 1024, 0, stream>>>(cnt, offs, bsum);
    scan_sums<<<1, 64, 0, stream>>>(bsum);
    scan_add<<<NBLK, 1024, 0, stream>>>(offs, bsum);
    hipMemsetAsync(cnt, 0, (size_t)NN * 4, stream);
    scatter_kernel<<<(ETOT + 255) / 256, 256, 0, stream>>>(ei, offs, cnt, srcs);
    hipMemsetAsync(A2 + (size_t)NN * FF, 0, (size_t)(MP - NN) * FF * 2, stream);
    prep_w2t<<<(FF * FF + 255) / 256, 256, 0, stream>>>(W2, W2T);
    prep_w3t<<<(48 * 512 + 255) / 256, 256, 0, stream>>>(W3, W3T);

    // ---- layer 1 ----
    gemm1_fused<<<(NN + 63) / 64, 256, 0, stream>>>(x, W1, as1, ad1, Hb1, alS, alD);
    attn_gather<<<(NN + 3) / 4, 256, 0, stream>>>(Hb1, alS, alD, offs, srcs, b1,
                                                  nullptr, A2, 1);

    // ---- layer 2: bf16 MFMA GEMM (+ fused logits), dbuf + L2-affinity swizzle
    gemm_mfma<<<GT2, 256, 0, stream>>>(
        A2, W2T, as2, ad2, Hb2, alS, alD, FF, FF);
    attn_gather<<<(NN + 3) / 4, 256, 0, stream>>>(Hb2, alS, alD, offs, srcs, b2,
                                                  nullptr, Bb16, 1);

    // ---- layer 3 ----
    gemm3_mfma<<<MP / 128, 256, 0, stream>>>(Bb16, W3T, h3);
    al40_kernel<<<(NN + 255) / 256, 256, 0, stream>>>(h3, as3, ad3, alS, alD);
    attn3_kernel<<<NN / 4, 256, 0, stream>>>(h3, alS, alD, offs, srcs, b3, out);
}